// Round 4
// baseline (527.301 us; speedup 1.0000x reference)
//
#include <hip/hip_runtime.h>

// 2-layer GCN, N=100000, E=1200000, dims 64, fp32 in/out.
//
// R4: aggregation was instruction/latency bound (R3: bytes -41% -> dur only
// -10%). Repack the per-node wave as 4 edge-slots x 16 feature-quads: each
// lane loads ushort4 (8B), so one VMEM instruction gathers 4 edge rows
// (512 B) and address/convert VALU work per edge drops ~4x. Cross-slot
// combine = 8 shfl_xor at loop end. 32-bit indices (saddr-form loads).
// GEMM: 16 rows/block, float4 W staging, 4 FMA per LDS read.

#define FEAT 64

__device__ __forceinline__ unsigned short f2bf(float f) {
    unsigned u = __float_as_uint(f);
    unsigned r = (u + 0x7FFFu + ((u >> 16) & 1u)) >> 16;   // RNE
    return (unsigned short)r;
}
__device__ __forceinline__ float bf2f(unsigned short h) {
    return __uint_as_float(((unsigned)h) << 16);
}

__global__ void k_hist(const int* __restrict__ dst, int* __restrict__ cnt, int E) {
    int e = blockIdx.x * blockDim.x + threadIdx.x;
    if (e < E) atomicAdd(&cnt[dst[e]], 1);
}

// scan pass 1 + fused dinv = rsqrt(cnt+1)
__global__ void k_scan1(const int* __restrict__ cnt, int* __restrict__ partial,
                        int* __restrict__ blockSum, float* __restrict__ dinv, int n) {
    __shared__ int s[256];
    int t = threadIdx.x;
    int i = blockIdx.x * 256 + t;
    int v = (i < n) ? cnt[i] : 0;
    if (i < n) dinv[i] = rsqrtf((float)v + 1.0f);
    s[t] = v;
    __syncthreads();
    for (int off = 1; off < 256; off <<= 1) {
        int x = (t >= off) ? s[t - off] : 0;
        __syncthreads();
        s[t] += x;
        __syncthreads();
    }
    if (i < n) partial[i] = s[t] - v;
    if (t == 255) blockSum[blockIdx.x] = s[255];
}

__global__ void k_scan2(int* __restrict__ blockSum, int nb) {
    __shared__ int s[512];
    int t = threadIdx.x;
    int v = (t < nb) ? blockSum[t] : 0;
    s[t] = v;
    __syncthreads();
    for (int off = 1; off < 512; off <<= 1) {
        int x = (t >= off) ? s[t - off] : 0;
        __syncthreads();
        s[t] += x;
        __syncthreads();
    }
    if (t < nb) blockSum[t] = s[t] - v;
}

__global__ void k_scan3(int* __restrict__ offs, const int* __restrict__ blockSum,
                        int* __restrict__ cursor, int n, int E) {
    int i = blockIdx.x * 256 + threadIdx.x;
    if (i < n) {
        int o = offs[i] + blockSum[blockIdx.x];
        offs[i] = o;
        cursor[i] = o;
    }
    if (i == 0) offs[n] = E;
}

__global__ void k_scatter(const int* __restrict__ src, const int* __restrict__ dst,
                          int* __restrict__ cursor, int* __restrict__ ssrc, int E) {
    int e = blockIdx.x * blockDim.x + threadIdx.x;
    if (e < E) {
        int p = atomicAdd(&cursor[dst[e]], 1);
        ssrc[p] = src[e];
    }
}

// H[n,64] = X[n,64] @ W[64,64], bf16 out. Block = 256 threads, 16 rows/block.
template <bool IN_BF16>
__global__ void __launch_bounds__(256)
k_gemm64(const void* __restrict__ Xv, const float* __restrict__ W,
         unsigned short* __restrict__ H, int n) {
    __shared__ float Ws[64][64];
    __shared__ float Xs[16][64];
    int tid = threadIdx.x;
    {
        const float4* Wv = (const float4*)W;
        float4* Wd = (float4*)&Ws[0][0];
        for (int i = tid; i < 1024; i += 256) Wd[i] = Wv[i];
    }
    int r = tid >> 6, col = tid & 63;
    int base = blockIdx.x * 16;
#pragma unroll
    for (int q = 0; q < 4; ++q) {
        int row = base + r + q * 4;
        float xv = 0.f;
        if (row < n) {
            unsigned idx = (unsigned)row * 64u + (unsigned)col;
            xv = IN_BF16 ? bf2f(((const unsigned short*)Xv)[idx])
                         : ((const float*)Xv)[idx];
        }
        Xs[r + q * 4][col] = xv;
    }
    __syncthreads();
    float a0 = 0.f, a1 = 0.f, a2 = 0.f, a3 = 0.f;
#pragma unroll
    for (int k = 0; k < 64; ++k) {
        float w = Ws[k][col];
        a0 += Xs[r][k] * w;
        a1 += Xs[r + 4][k] * w;
        a2 += Xs[r + 8][k] * w;
        a3 += Xs[r + 12][k] * w;
    }
    unsigned rb = (unsigned)base * 64u + (unsigned)r * 64u + (unsigned)col;
    if (base + r      < n) H[rb            ] = f2bf(a0);
    if (base + r + 4  < n) H[rb + 4  * 64u ] = f2bf(a1);
    if (base + r + 8  < n) H[rb + 8  * 64u ] = f2bf(a2);
    if (base + r + 12 < n) H[rb + 12 * 64u ] = f2bf(a3);
}

// One wave per node. Lanes = 4 edge-slots (g) x 16 feature-quads (fq).
// Each lane gathers ushort4 (8B); one wave iteration covers 4 edges.
__global__ void __launch_bounds__(256)
k_agg_csr(const int* __restrict__ offs, const int* __restrict__ ssrc,
          const float* __restrict__ dinv, const unsigned short* __restrict__ H,
          const float* __restrict__ bias, unsigned short* __restrict__ out, int n) {
    int node = blockIdx.x * 4 + (threadIdx.x >> 6);
    if (node >= n) return;
    int lane = threadIdx.x & 63;
    int g = lane >> 4, fq = lane & 15;
    int beg = offs[node], end = offs[node + 1];
    float dd = dinv[node];
    float ax = 0.f, ay = 0.f, az = 0.f, aw = 0.f;
    for (int j = beg + g; j < end; j += 4) {
        int s = ssrc[j];
        float nn = dinv[s] * dd;
        ushort4 hv = *((const ushort4*)(H + ((unsigned)s << 6)) + fq);
        ax += bf2f(hv.x) * nn;
        ay += bf2f(hv.y) * nn;
        az += bf2f(hv.z) * nn;
        aw += bf2f(hv.w) * nn;
    }
    ax += __shfl_xor(ax, 16); ay += __shfl_xor(ay, 16);
    az += __shfl_xor(az, 16); aw += __shfl_xor(aw, 16);
    ax += __shfl_xor(ax, 32); ay += __shfl_xor(ay, 32);
    az += __shfl_xor(az, 32); aw += __shfl_xor(aw, 32);
    if (g == 0) {
        ushort4 sv = *((const ushort4*)(H + ((unsigned)node << 6)) + fq);
        float d2 = dd * dd;
        float4 bv = ((const float4*)bias)[fq];
        ushort4 o;
        o.x = f2bf(fmaxf(ax + bf2f(sv.x) * d2 + bv.x, 0.f));
        o.y = f2bf(fmaxf(ay + bf2f(sv.y) * d2 + bv.y, 0.f));
        o.z = f2bf(fmaxf(az + bf2f(sv.z) * d2 + bv.z, 0.f));
        o.w = f2bf(fmaxf(aw + bf2f(sv.w) * d2 + bv.w, 0.f));
        *((ushort4*)(out + ((unsigned)node << 6)) + fq) = o;
    }
}

// Layer-2 aggregation (same scheme) fused with final linear out = t@Wl + bl.
__global__ void __launch_bounds__(256)
k_agg_final(const int* __restrict__ offs, const int* __restrict__ ssrc,
            const float* __restrict__ dinv, const unsigned short* __restrict__ H,
            const float* __restrict__ b2, const float* __restrict__ Wl,
            const float* __restrict__ bl, float* __restrict__ out, int n) {
    __shared__ float Ws[64][64];
    __shared__ float Ts[4][64];
    int tid = threadIdx.x;
    {
        const float4* Wv = (const float4*)Wl;
        float4* Wd = (float4*)&Ws[0][0];
        for (int i = tid; i < 1024; i += 256) Wd[i] = Wv[i];
    }
    int r = tid >> 6, lane = tid & 63;
    int node = blockIdx.x * 4 + r;
    int g = lane >> 4, fq = lane & 15;
    if (node < n) {
        int beg = offs[node], end = offs[node + 1];
        float dd = dinv[node];
        float ax = 0.f, ay = 0.f, az = 0.f, aw = 0.f;
        for (int j = beg + g; j < end; j += 4) {
            int s = ssrc[j];
            float nn = dinv[s] * dd;
            ushort4 hv = *((const ushort4*)(H + ((unsigned)s << 6)) + fq);
            ax += bf2f(hv.x) * nn;
            ay += bf2f(hv.y) * nn;
            az += bf2f(hv.z) * nn;
            aw += bf2f(hv.w) * nn;
        }
        ax += __shfl_xor(ax, 16); ay += __shfl_xor(ay, 16);
        az += __shfl_xor(az, 16); aw += __shfl_xor(aw, 16);
        ax += __shfl_xor(ax, 32); ay += __shfl_xor(ay, 32);
        az += __shfl_xor(az, 32); aw += __shfl_xor(aw, 32);
        if (g == 0) {
            ushort4 sv = *((const ushort4*)(H + ((unsigned)node << 6)) + fq);
            float d2 = dd * dd;
            float4 bv = ((const float4*)b2)[fq];
            float4 t;
            t.x = ax + bf2f(sv.x) * d2 + bv.x;
            t.y = ay + bf2f(sv.y) * d2 + bv.y;
            t.z = az + bf2f(sv.z) * d2 + bv.z;
            t.w = aw + bf2f(sv.w) * d2 + bv.w;
            ((float4*)&Ts[r][0])[fq] = t;
        }
    }
    __syncthreads();
    if (node >= n) return;
    float acc = bl[lane];
#pragma unroll
    for (int k = 0; k < 64; ++k) acc += Ts[r][k] * Ws[k][lane];
    out[(unsigned)node * 64u + (unsigned)lane] = acc;
}

extern "C" void kernel_launch(void* const* d_in, const int* in_sizes, int n_in,
                              void* d_out, int out_size, void* d_ws, size_t ws_size,
                              hipStream_t stream) {
    const float* x  = (const float*)d_in[0];
    const int*   ei = (const int*)d_in[1];   // [2][E] int32
    const float* W1 = (const float*)d_in[2];
    const float* b1 = (const float*)d_in[3];
    const float* W2 = (const float*)d_in[4];
    const float* b2 = (const float*)d_in[5];
    const float* Wl = (const float*)d_in[6];
    const float* bl = (const float*)d_in[7];
    float* out = (float*)d_out;

    const int n = in_sizes[0] / FEAT;   // 100000
    const int E = in_sizes[1] / 2;      // 1200000
    const int* src = ei;
    const int* dst = ei + E;

    const int B = 256;
    const int nblocks = (n + B - 1) / B;
    const int eblocks = (E + B - 1) / B;
    const int agg_blocks  = (n + 3) / 4;
    const int gemm_blocks = (n + 15) / 16;

    char* w = (char*)d_ws;
    int*   cnt      = (int*)w;              w += (size_t)n * 4;
    int*   offs     = (int*)w;              w += ((size_t)n + 1) * 4;
    int*   cursor   = (int*)w;              w += (size_t)n * 4;
    int*   blockSum = (int*)w;              w += 512 * 4;
    int*   ssrc     = (int*)w;              w += (size_t)E * 4;
    float* dinv     = (float*)w;            w += (size_t)n * 4;
    w = (char*)(((uintptr_t)w + 15) & ~(uintptr_t)15);
    unsigned short* bufA = (unsigned short*)w;  w += (size_t)n * FEAT * 2;  // h1 / h3
    unsigned short* bufB = (unsigned short*)w;                              // h2

    // ---- CSR build ----
    hipMemsetAsync(cnt, 0, (size_t)n * 4, stream);
    k_hist<<<dim3(eblocks), dim3(B), 0, stream>>>(dst, cnt, E);
    k_scan1<<<dim3(nblocks), dim3(B), 0, stream>>>(cnt, offs, blockSum, dinv, n);
    k_scan2<<<dim3(1), dim3(512), 0, stream>>>(blockSum, nblocks);
    k_scan3<<<dim3(nblocks), dim3(B), 0, stream>>>(offs, blockSum, cursor, n, E);
    k_scatter<<<dim3(eblocks), dim3(B), 0, stream>>>(src, dst, cursor, ssrc, E);

    // ---- layer 1 ----
    k_gemm64<false><<<dim3(gemm_blocks), dim3(B), 0, stream>>>(x, W1, bufA, n);
    k_agg_csr<<<dim3(agg_blocks), dim3(B), 0, stream>>>(offs, ssrc, dinv, bufA, b1, bufB, n);

    // ---- layer 2 + final linear ----
    k_gemm64<true><<<dim3(gemm_blocks), dim3(B), 0, stream>>>(bufB, W2, bufA, n);
    k_agg_final<<<dim3(agg_blocks), dim3(B), 0, stream>>>(offs, ssrc, dinv, bufA, b2, Wl, bl, out, n);
}

// Round 5
// 418.256 us; speedup vs baseline: 1.2607x; 1.2607x over previous
//
#include <hip/hip_runtime.h>

// 2-layer GCN, N=100000, E=1200000, dims 64, fp32 in/out.
//
// R5: (a) GEMM 4x4 register tiling (8x ds_read_b128 per 64 FMA, 2B/FMA,
// VGPR~64) after R4's 140-VGPR/10%-occupancy regression. (b) edge norm
// precomputed in scatter (edata = {src, norm}): one dependent load level in
// agg instead of two; self-norm = 1/(deg+1) from offs. (c) agg = 8 edge
// slots x 8 lanes x 16B loads. Final linear is a plain 3rd GEMM call.

#define FEAT 64

__device__ __forceinline__ unsigned short f2bf(float f) {
    unsigned u = __float_as_uint(f);
    return (unsigned short)((u + 0x7FFFu + ((u >> 16) & 1u)) >> 16);   // RNE
}
__device__ __forceinline__ float bf2f(unsigned short h) {
    return __uint_as_float(((unsigned)h) << 16);
}
__device__ __forceinline__ float bflo(unsigned u) { return __uint_as_float(u << 16); }
__device__ __forceinline__ float bfhi(unsigned u) { return __uint_as_float(u & 0xFFFF0000u); }
__device__ __forceinline__ unsigned packbf(float a, float b) {
    return (unsigned)f2bf(a) | ((unsigned)f2bf(b) << 16);
}
__device__ __forceinline__ void fma4(float4& acc, float s, const float4& b) {
    acc.x += s * b.x; acc.y += s * b.y; acc.z += s * b.z; acc.w += s * b.w;
}

__global__ void k_hist(const int* __restrict__ dst, int* __restrict__ cnt, int E) {
    int e = blockIdx.x * blockDim.x + threadIdx.x;
    if (e < E) atomicAdd(&cnt[dst[e]], 1);
}

// scan pass 1 + fused dinv = rsqrt(cnt+1)
__global__ void k_scan1(const int* __restrict__ cnt, int* __restrict__ partial,
                        int* __restrict__ blockSum, float* __restrict__ dinv, int n) {
    __shared__ int s[256];
    int t = threadIdx.x;
    int i = blockIdx.x * 256 + t;
    int v = (i < n) ? cnt[i] : 0;
    if (i < n) dinv[i] = rsqrtf((float)v + 1.0f);
    s[t] = v;
    __syncthreads();
    for (int off = 1; off < 256; off <<= 1) {
        int x = (t >= off) ? s[t - off] : 0;
        __syncthreads();
        s[t] += x;
        __syncthreads();
    }
    if (i < n) partial[i] = s[t] - v;
    if (t == 255) blockSum[blockIdx.x] = s[255];
}

__global__ void k_scan2(int* __restrict__ blockSum, int nb) {
    __shared__ int s[512];
    int t = threadIdx.x;
    int v = (t < nb) ? blockSum[t] : 0;
    s[t] = v;
    __syncthreads();
    for (int off = 1; off < 512; off <<= 1) {
        int x = (t >= off) ? s[t - off] : 0;
        __syncthreads();
        s[t] += x;
        __syncthreads();
    }
    if (t < nb) blockSum[t] = s[t] - v;
}

__global__ void k_scan3(int* __restrict__ offs, const int* __restrict__ blockSum,
                        int* __restrict__ cursor, int n, int E) {
    int i = blockIdx.x * 256 + threadIdx.x;
    if (i < n) {
        int o = offs[i] + blockSum[blockIdx.x];
        offs[i] = o;
        cursor[i] = o;
    }
    if (i == 0) offs[n] = E;
}

// counting-sort scatter; also precomputes the edge norm dinv[s]*dinv[d].
__global__ void k_scatter(const int* __restrict__ src, const int* __restrict__ dst,
                          const float* __restrict__ dinv, int* __restrict__ cursor,
                          int2* __restrict__ edata, int E) {
    int e = blockIdx.x * blockDim.x + threadIdx.x;
    if (e < E) {
        int s = src[e], d = dst[e];
        int p = atomicAdd(&cursor[d], 1);
        edata[p] = make_int2(s, __float_as_int(dinv[s] * dinv[d]));
    }
}

// H[n,64] = X[n,64] @ W[64,64] (+bias if OUT_F32). Block = 256 thr = 64 rows.
// Thread computes 4 rows x 4 cols; per 4-k-block: 8 ds_read_b128 -> 64 FMA.
template <bool IN_BF16, bool OUT_F32>
__global__ void __launch_bounds__(256)
k_gemm64t(const void* __restrict__ Xv, const float* __restrict__ W,
          const float* __restrict__ bias, void* __restrict__ Hv, int n) {
    __shared__ float Xs[64][68];   // row-major, +4 pad keeps 16B align & banks spread
    __shared__ float Ws[64][64];
    int tid = threadIdx.x;
    {
        const float4* Wv4 = (const float4*)W;
        float4* Wd = (float4*)&Ws[0][0];
        for (int i = tid; i < 1024; i += 256) Wd[i] = Wv4[i];
    }
    int base = blockIdx.x * 64;
#pragma unroll
    for (int q = 0; q < 4; ++q) {
        int fid = q * 256 + tid;
        int r = fid >> 4, cq = fid & 15;
        int row = base + r;
        float4 xv = make_float4(0.f, 0.f, 0.f, 0.f);
        if (row < n) {
            if (IN_BF16) {
                ushort4 uv = ((const ushort4*)Xv)[(unsigned)row * 16u + cq];
                xv = make_float4(bf2f(uv.x), bf2f(uv.y), bf2f(uv.z), bf2f(uv.w));
            } else {
                xv = ((const float4*)Xv)[(unsigned)row * 16u + cq];
            }
        }
        *(float4*)&Xs[r][cq * 4] = xv;
    }
    __syncthreads();
    int rg = tid >> 4, cg = tid & 15;
    float4 acc0 = make_float4(0.f, 0.f, 0.f, 0.f), acc1 = acc0, acc2 = acc0, acc3 = acc0;
    int r4 = rg * 4, c4 = cg * 4;
#pragma unroll
    for (int k4 = 0; k4 < 16; ++k4) {
        int k = k4 * 4;
        float4 a0 = *(const float4*)&Xs[r4 + 0][k];
        float4 a1 = *(const float4*)&Xs[r4 + 1][k];
        float4 a2 = *(const float4*)&Xs[r4 + 2][k];
        float4 a3 = *(const float4*)&Xs[r4 + 3][k];
        float4 b0 = *(const float4*)&Ws[k + 0][c4];
        float4 b1 = *(const float4*)&Ws[k + 1][c4];
        float4 b2 = *(const float4*)&Ws[k + 2][c4];
        float4 b3 = *(const float4*)&Ws[k + 3][c4];
        fma4(acc0, a0.x, b0); fma4(acc0, a0.y, b1); fma4(acc0, a0.z, b2); fma4(acc0, a0.w, b3);
        fma4(acc1, a1.x, b0); fma4(acc1, a1.y, b1); fma4(acc1, a1.z, b2); fma4(acc1, a1.w, b3);
        fma4(acc2, a2.x, b0); fma4(acc2, a2.y, b1); fma4(acc2, a2.z, b2); fma4(acc2, a2.w, b3);
        fma4(acc3, a3.x, b0); fma4(acc3, a3.y, b1); fma4(acc3, a3.z, b2); fma4(acc3, a3.w, b3);
    }
    float4 av[4] = {acc0, acc1, acc2, acc3};
#pragma unroll
    for (int i = 0; i < 4; ++i) {
        int row = base + r4 + i;
        if (row >= n) break;
        if (OUT_F32) {
            float4 bv = ((const float4*)bias)[cg];
            float4 o = make_float4(av[i].x + bv.x, av[i].y + bv.y,
                                   av[i].z + bv.z, av[i].w + bv.w);
            ((float4*)Hv)[(unsigned)row * 16u + cg] = o;
        } else {
            ushort4 o;
            o.x = f2bf(av[i].x); o.y = f2bf(av[i].y);
            o.z = f2bf(av[i].z); o.w = f2bf(av[i].w);
            ((ushort4*)Hv)[(unsigned)row * 16u + cg] = o;
        }
    }
}

// One wave per node. 8 edge-slots (g) x 8 lanes (h8); each lane loads 16B
// (8 bf16 feats). Single 8B edata stream load per edge; self-norm from deg.
__global__ void __launch_bounds__(256)
k_agg(const int* __restrict__ offs, const int2* __restrict__ edata,
      const unsigned short* __restrict__ H, const float* __restrict__ bias,
      unsigned short* __restrict__ out, int n, int relu) {
    int node = blockIdx.x * 4 + (threadIdx.x >> 6);
    if (node >= n) return;
    int lane = threadIdx.x & 63;
    int g = lane >> 3, h8 = lane & 7;
    int beg = offs[node], end = offs[node + 1];
    float a0 = 0.f, a1 = 0.f, a2 = 0.f, a3 = 0.f, a4 = 0.f, a5 = 0.f, a6 = 0.f, a7 = 0.f;
    for (int j = beg + g; j < end; j += 8) {
        int2 e = edata[j];
        float nn = __int_as_float(e.y);
        uint4 hv = *(const uint4*)(H + ((unsigned)e.x << 6) + (h8 << 3));
        a0 += bflo(hv.x) * nn; a1 += bfhi(hv.x) * nn;
        a2 += bflo(hv.y) * nn; a3 += bfhi(hv.y) * nn;
        a4 += bflo(hv.z) * nn; a5 += bfhi(hv.z) * nn;
        a6 += bflo(hv.w) * nn; a7 += bfhi(hv.w) * nn;
    }
#pragma unroll
    for (int m = 8; m < 64; m <<= 1) {
        a0 += __shfl_xor(a0, m); a1 += __shfl_xor(a1, m);
        a2 += __shfl_xor(a2, m); a3 += __shfl_xor(a3, m);
        a4 += __shfl_xor(a4, m); a5 += __shfl_xor(a5, m);
        a6 += __shfl_xor(a6, m); a7 += __shfl_xor(a7, m);
    }
    if (g == 0) {
        float d2 = 1.0f / (float)(end - beg + 1);   // dinv^2 of this node
        uint4 sv = *(const uint4*)(H + ((unsigned)node << 6) + (h8 << 3));
        const float4* b4 = (const float4*)bias;
        float4 bA = b4[h8 * 2], bB = b4[h8 * 2 + 1];
        float r0 = a0 + bflo(sv.x) * d2 + bA.x;
        float r1 = a1 + bfhi(sv.x) * d2 + bA.y;
        float r2 = a2 + bflo(sv.y) * d2 + bA.z;
        float r3 = a3 + bfhi(sv.y) * d2 + bA.w;
        float r4 = a4 + bflo(sv.z) * d2 + bB.x;
        float r5 = a5 + bfhi(sv.z) * d2 + bB.y;
        float r6 = a6 + bflo(sv.w) * d2 + bB.z;
        float r7 = a7 + bfhi(sv.w) * d2 + bB.w;
        if (relu) {
            r0 = fmaxf(r0, 0.f); r1 = fmaxf(r1, 0.f); r2 = fmaxf(r2, 0.f); r3 = fmaxf(r3, 0.f);
            r4 = fmaxf(r4, 0.f); r5 = fmaxf(r5, 0.f); r6 = fmaxf(r6, 0.f); r7 = fmaxf(r7, 0.f);
        }
        uint4 o;
        o.x = packbf(r0, r1); o.y = packbf(r2, r3);
        o.z = packbf(r4, r5); o.w = packbf(r6, r7);
        *(uint4*)(out + ((unsigned)node << 6) + (h8 << 3)) = o;
    }
}

extern "C" void kernel_launch(void* const* d_in, const int* in_sizes, int n_in,
                              void* d_out, int out_size, void* d_ws, size_t ws_size,
                              hipStream_t stream) {
    const float* x  = (const float*)d_in[0];
    const int*   ei = (const int*)d_in[1];   // [2][E] int32
    const float* W1 = (const float*)d_in[2];
    const float* b1 = (const float*)d_in[3];
    const float* W2 = (const float*)d_in[4];
    const float* b2 = (const float*)d_in[5];
    const float* Wl = (const float*)d_in[6];
    const float* bl = (const float*)d_in[7];
    float* out = (float*)d_out;

    const int n = in_sizes[0] / FEAT;   // 100000
    const int E = in_sizes[1] / 2;      // 1200000
    const int* src = ei;
    const int* dst = ei + E;

    const int B = 256;
    const int nblocks = (n + B - 1) / B;
    const int eblocks = (E + B - 1) / B;
    const int agg_blocks  = (n + 3) / 4;
    const int gemm_blocks = (n + 63) / 64;

    char* w = (char*)d_ws;
    int*   cnt      = (int*)w;              w += (size_t)n * 4;
    int*   offs     = (int*)w;              w += ((size_t)n + 1) * 4;
    int*   cursor   = (int*)w;              w += (size_t)n * 4;
    int*   blockSum = (int*)w;              w += 512 * 4;
    float* dinv     = (float*)w;            w += (size_t)n * 4;
    w = (char*)(((uintptr_t)w + 15) & ~(uintptr_t)15);
    int2*  edata    = (int2*)w;             w += (size_t)E * 8;
    unsigned short* bufA = (unsigned short*)w;  w += (size_t)n * FEAT * 2;  // h1 / h3
    unsigned short* bufB = (unsigned short*)w;                              // h2 / t

    // ---- CSR build ----
    hipMemsetAsync(cnt, 0, (size_t)n * 4, stream);
    k_hist<<<dim3(eblocks), dim3(B), 0, stream>>>(dst, cnt, E);
    k_scan1<<<dim3(nblocks), dim3(B), 0, stream>>>(cnt, offs, blockSum, dinv, n);
    k_scan2<<<dim3(1), dim3(512), 0, stream>>>(blockSum, nblocks);
    k_scan3<<<dim3(nblocks), dim3(B), 0, stream>>>(offs, blockSum, cursor, n, E);
    k_scatter<<<dim3(eblocks), dim3(B), 0, stream>>>(src, dst, dinv, cursor, edata, E);

    // ---- layer 1 ----
    k_gemm64t<false, false><<<dim3(gemm_blocks), dim3(B), 0, stream>>>(x, W1, nullptr, bufA, n);
    k_agg<<<dim3(agg_blocks), dim3(B), 0, stream>>>(offs, edata, bufA, b1, bufB, n, 1);

    // ---- layer 2 ----
    k_gemm64t<true, false><<<dim3(gemm_blocks), dim3(B), 0, stream>>>(bufB, W2, nullptr, bufA, n);
    k_agg<<<dim3(agg_blocks), dim3(B), 0, stream>>>(offs, edata, bufA, b2, bufB, n, 0);

    // ---- final linear ----
    k_gemm64t<true, true><<<dim3(gemm_blocks), dim3(B), 0, stream>>>(bufB, Wl, bl, out, n);
}

// Round 6
// 347.370 us; speedup vs baseline: 1.5180x; 1.2041x over previous
//
#include <hip/hip_runtime.h>

// 2-layer GCN, N=100000, E=1200000, dims 64, fp32 in/out.
//
// R6: CSR build overhaul. R5's k_scatter was 80 us: 1.2M random 8B writes ->
// 64B-line writebacks (WRITE_SIZE 78 MB = 8x amplification) + random global
// atomics bouncing across XCDs. Replace hist+scatter with a bucketed
// counting sort (512-node buckets): (A) bucket histogram, (B) 256-scan,
// (C) partition with LDS ranks -> packed 4B (src<<9|dstLocal) in contiguous
// runs, (D1) per-bucket LDS node-hist -> coalesced cnt, (D2) per-bucket
// final scatter with LDS ranks only -> 8B edata into a 50 KB L2-local
// region. Zero random global atomics, ~1x write amplification.
// Agg: prefetch next edata record past the dependent row gather.

#define FEAT 64

__device__ __forceinline__ unsigned short f2bf(float f) {
    unsigned u = __float_as_uint(f);
    return (unsigned short)((u + 0x7FFFu + ((u >> 16) & 1u)) >> 16);   // RNE
}
__device__ __forceinline__ float bf2f(unsigned short h) {
    return __uint_as_float(((unsigned)h) << 16);
}
__device__ __forceinline__ float bflo(unsigned u) { return __uint_as_float(u << 16); }
__device__ __forceinline__ float bfhi(unsigned u) { return __uint_as_float(u & 0xFFFF0000u); }
__device__ __forceinline__ unsigned packbf(float a, float b) {
    return (unsigned)f2bf(a) | ((unsigned)f2bf(b) << 16);
}
__device__ __forceinline__ void fma4(float4& acc, float s, const float4& b) {
    acc.x += s * b.x; acc.y += s * b.y; acc.z += s * b.z; acc.w += s * b.w;
}

// ---- A: bucket histogram (bucket = dst >> 9) ----
__global__ void __launch_bounds__(256)
k_bhist(const int* __restrict__ dst, int* __restrict__ bcnt, int E) {
    __shared__ int h[256];
    int tid = threadIdx.x;
    h[tid] = 0;
    __syncthreads();
    int stride = gridDim.x * 256;
    for (int e = blockIdx.x * 256 + tid; e < E; e += stride)
        atomicAdd(&h[dst[e] >> 9], 1);
    __syncthreads();
    if (h[tid]) atomicAdd(&bcnt[tid], h[tid]);
}

// ---- B: exclusive scan of 256 bucket counts -> bbase (257 wide) + bcur ----
__global__ void k_bscan(const int* __restrict__ bcnt, int* __restrict__ bbase,
                        int* __restrict__ bcur) {
    __shared__ int s[256];
    int t = threadIdx.x;
    int v = bcnt[t];
    s[t] = v;
    __syncthreads();
    for (int off = 1; off < 256; off <<= 1) {
        int x = (t >= off) ? s[t - off] : 0;
        __syncthreads();
        s[t] += x;
        __syncthreads();
    }
    int ex = s[t] - v;
    bbase[t] = ex;
    bcur[t] = ex;
    if (t == 255) bbase[256] = s[255];
}

// ---- C: partition edges into buckets, packed (src<<9 | dst&511) ----
__global__ void __launch_bounds__(256)
k_part(const int* __restrict__ src, const int* __restrict__ dst,
       int* __restrict__ bcur, unsigned* __restrict__ pass1, int E) {
    __shared__ unsigned pk[4096];
    __shared__ unsigned char bk[4096];
    __shared__ int h[256];
    __shared__ int cur[256];
    int tid = threadIdx.x;
    h[tid] = 0;
    __syncthreads();
    int base = blockIdx.x * 4096;
#pragma unroll
    for (int i = 0; i < 16; ++i) {
        int li = i * 256 + tid;
        int e = base + li;
        if (e < E) {
            int s = src[e], d = dst[e];
            int b = d >> 9;
            pk[li] = ((unsigned)s << 9) | ((unsigned)d & 511u);
            bk[li] = (unsigned char)b;
            atomicAdd(&h[b], 1);
        } else {
            bk[li] = 255;  // sentinel: bucket 255 is empty for n=100000
            pk[li] = 0xFFFFFFFFu;
        }
    }
    __syncthreads();
    {
        int c = h[tid];
        int run = c ? atomicAdd(&bcur[tid], c) : 0;
        cur[tid] = run;
    }
    __syncthreads();
#pragma unroll
    for (int i = 0; i < 16; ++i) {
        int li = i * 256 + tid;
        int e = base + li;
        if (e < E) {
            int b = bk[li];
            int pos = atomicAdd(&cur[b], 1);
            pass1[pos] = pk[li];
        }
    }
}

// ---- D1: per-bucket node histogram -> cnt (coalesced, no global atomics) ----
__global__ void __launch_bounds__(256)
k_nhist(const unsigned* __restrict__ pass1, const int* __restrict__ bbase,
        int* __restrict__ cnt, int n) {
    __shared__ int h[512];
    int tid = threadIdx.x;
    h[tid] = 0; h[tid + 256] = 0;
    __syncthreads();
    int b = blockIdx.x;
    int beg = bbase[b], end = bbase[b + 1];
    for (int j = beg + tid; j < end; j += 256)
        atomicAdd(&h[pass1[j] & 511u], 1);
    __syncthreads();
    int nb = b << 9;
#pragma unroll
    for (int q = 0; q < 2; ++q) {
        int t2 = tid + q * 256;
        int node = nb + t2;
        if (node < n) cnt[node] = h[t2];
    }
}

// ---- scan over cnt (offs) + fused dinv ----
__global__ void k_scan1(const int* __restrict__ cnt, int* __restrict__ partial,
                        int* __restrict__ blockSum, float* __restrict__ dinv, int n) {
    __shared__ int s[256];
    int t = threadIdx.x;
    int i = blockIdx.x * 256 + t;
    int v = (i < n) ? cnt[i] : 0;
    if (i < n) dinv[i] = rsqrtf((float)v + 1.0f);
    s[t] = v;
    __syncthreads();
    for (int off = 1; off < 256; off <<= 1) {
        int x = (t >= off) ? s[t - off] : 0;
        __syncthreads();
        s[t] += x;
        __syncthreads();
    }
    if (i < n) partial[i] = s[t] - v;
    if (t == 255) blockSum[blockIdx.x] = s[255];
}

__global__ void k_scan2(int* __restrict__ blockSum, int nb) {
    __shared__ int s[512];
    int t = threadIdx.x;
    int v = (t < nb) ? blockSum[t] : 0;
    s[t] = v;
    __syncthreads();
    for (int off = 1; off < 512; off <<= 1) {
        int x = (t >= off) ? s[t - off] : 0;
        __syncthreads();
        s[t] += x;
        __syncthreads();
    }
    if (t < nb) blockSum[t] = s[t] - v;
}

__global__ void k_scan3(int* __restrict__ offs, const int* __restrict__ blockSum,
                        int n, int E) {
    int i = blockIdx.x * 256 + threadIdx.x;
    if (i < n) offs[i] += blockSum[blockIdx.x];
    if (i == 0) offs[n] = E;
}

// ---- D2: per-bucket final scatter; ranks via LDS, edata = (src, norm) ----
__global__ void __launch_bounds__(256)
k_fscatter(const unsigned* __restrict__ pass1, const int* __restrict__ bbase,
           const int* __restrict__ offs, const float* __restrict__ dinv,
           int2* __restrict__ edata) {
    __shared__ int cur[512];
    int tid = threadIdx.x;
    cur[tid] = 0; cur[tid + 256] = 0;
    __syncthreads();
    int b = blockIdx.x;
    int beg = bbase[b], end = bbase[b + 1];
    int nb = b << 9;
    for (int j = beg + tid; j < end; j += 256) {
        unsigned u = pass1[j];
        int loc = (int)(u & 511u);
        int s = (int)(u >> 9);
        int node = nb + loc;
        int r = atomicAdd(&cur[loc], 1);
        int pos = offs[node] + r;
        edata[pos] = make_int2(s, __float_as_int(dinv[s] * dinv[node]));
    }
}

// ---- GEMM: H[n,64] = X[n,64] @ W[64,64] (+bias if OUT_F32) ----
template <bool IN_BF16, bool OUT_F32>
__global__ void __launch_bounds__(256)
k_gemm64t(const void* __restrict__ Xv, const float* __restrict__ W,
          const float* __restrict__ bias, void* __restrict__ Hv, int n) {
    __shared__ float Xs[64][68];
    __shared__ float Ws[64][64];
    int tid = threadIdx.x;
    {
        const float4* Wv4 = (const float4*)W;
        float4* Wd = (float4*)&Ws[0][0];
        for (int i = tid; i < 1024; i += 256) Wd[i] = Wv4[i];
    }
    int base = blockIdx.x * 64;
#pragma unroll
    for (int q = 0; q < 4; ++q) {
        int fid = q * 256 + tid;
        int r = fid >> 4, cq = fid & 15;
        int row = base + r;
        float4 xv = make_float4(0.f, 0.f, 0.f, 0.f);
        if (row < n) {
            if (IN_BF16) {
                ushort4 uv = ((const ushort4*)Xv)[(unsigned)row * 16u + cq];
                xv = make_float4(bf2f(uv.x), bf2f(uv.y), bf2f(uv.z), bf2f(uv.w));
            } else {
                xv = ((const float4*)Xv)[(unsigned)row * 16u + cq];
            }
        }
        *(float4*)&Xs[r][cq * 4] = xv;
    }
    __syncthreads();
    int rg = tid >> 4, cg = tid & 15;
    float4 acc0 = make_float4(0.f, 0.f, 0.f, 0.f), acc1 = acc0, acc2 = acc0, acc3 = acc0;
    int r4 = rg * 4, c4 = cg * 4;
#pragma unroll
    for (int k4 = 0; k4 < 16; ++k4) {
        int k = k4 * 4;
        float4 a0 = *(const float4*)&Xs[r4 + 0][k];
        float4 a1 = *(const float4*)&Xs[r4 + 1][k];
        float4 a2 = *(const float4*)&Xs[r4 + 2][k];
        float4 a3 = *(const float4*)&Xs[r4 + 3][k];
        float4 b0 = *(const float4*)&Ws[k + 0][c4];
        float4 b1 = *(const float4*)&Ws[k + 1][c4];
        float4 b2 = *(const float4*)&Ws[k + 2][c4];
        float4 b3 = *(const float4*)&Ws[k + 3][c4];
        fma4(acc0, a0.x, b0); fma4(acc0, a0.y, b1); fma4(acc0, a0.z, b2); fma4(acc0, a0.w, b3);
        fma4(acc1, a1.x, b0); fma4(acc1, a1.y, b1); fma4(acc1, a1.z, b2); fma4(acc1, a1.w, b3);
        fma4(acc2, a2.x, b0); fma4(acc2, a2.y, b1); fma4(acc2, a2.z, b2); fma4(acc2, a2.w, b3);
        fma4(acc3, a3.x, b0); fma4(acc3, a3.y, b1); fma4(acc3, a3.z, b2); fma4(acc3, a3.w, b3);
    }
    float4 av[4] = {acc0, acc1, acc2, acc3};
#pragma unroll
    for (int i = 0; i < 4; ++i) {
        int row = base + r4 + i;
        if (row >= n) break;
        if (OUT_F32) {
            float4 bv = ((const float4*)bias)[cg];
            float4 o = make_float4(av[i].x + bv.x, av[i].y + bv.y,
                                   av[i].z + bv.z, av[i].w + bv.w);
            ((float4*)Hv)[(unsigned)row * 16u + cg] = o;
        } else {
            ushort4 o;
            o.x = f2bf(av[i].x); o.y = f2bf(av[i].y);
            o.z = f2bf(av[i].z); o.w = f2bf(av[i].w);
            ((ushort4*)Hv)[(unsigned)row * 16u + cg] = o;
        }
    }
}

// ---- aggregation: one wave/node, 8 edge-slots x 8 lanes x 16B gathers,
//      edata prefetched one slot-iteration ahead ----
__global__ void __launch_bounds__(256)
k_agg(const int* __restrict__ offs, const int2* __restrict__ edata,
      const unsigned short* __restrict__ H, const float* __restrict__ bias,
      unsigned short* __restrict__ out, int n, int relu) {
    int node = blockIdx.x * 4 + (threadIdx.x >> 6);
    if (node >= n) return;
    int lane = threadIdx.x & 63;
    int g = lane >> 3, h8 = lane & 7;
    int beg = offs[node], end = offs[node + 1];
    float a0 = 0.f, a1 = 0.f, a2 = 0.f, a3 = 0.f, a4 = 0.f, a5 = 0.f, a6 = 0.f, a7 = 0.f;
    int j = beg + g;
    if (j < end) {
        int2 e = edata[j];
        for (;;) {
            int jn = j + 8;
            bool more = jn < end;
            int2 en = more ? edata[jn] : make_int2(0, 0);   // prefetch
            float nn = __int_as_float(e.y);
            uint4 hv = *(const uint4*)(H + ((unsigned)e.x << 6) + (h8 << 3));
            a0 += bflo(hv.x) * nn; a1 += bfhi(hv.x) * nn;
            a2 += bflo(hv.y) * nn; a3 += bfhi(hv.y) * nn;
            a4 += bflo(hv.z) * nn; a5 += bfhi(hv.z) * nn;
            a6 += bflo(hv.w) * nn; a7 += bfhi(hv.w) * nn;
            if (!more) break;
            e = en; j = jn;
        }
    }
#pragma unroll
    for (int m = 8; m < 64; m <<= 1) {
        a0 += __shfl_xor(a0, m); a1 += __shfl_xor(a1, m);
        a2 += __shfl_xor(a2, m); a3 += __shfl_xor(a3, m);
        a4 += __shfl_xor(a4, m); a5 += __shfl_xor(a5, m);
        a6 += __shfl_xor(a6, m); a7 += __shfl_xor(a7, m);
    }
    if (g == 0) {
        float d2 = 1.0f / (float)(end - beg + 1);   // dinv^2 of this node
        uint4 sv = *(const uint4*)(H + ((unsigned)node << 6) + (h8 << 3));
        const float4* b4 = (const float4*)bias;
        float4 bA = b4[h8 * 2], bB = b4[h8 * 2 + 1];
        float r0 = a0 + bflo(sv.x) * d2 + bA.x;
        float r1 = a1 + bfhi(sv.x) * d2 + bA.y;
        float r2 = a2 + bflo(sv.y) * d2 + bA.z;
        float r3 = a3 + bfhi(sv.y) * d2 + bA.w;
        float r4 = a4 + bflo(sv.z) * d2 + bB.x;
        float r5 = a5 + bfhi(sv.z) * d2 + bB.y;
        float r6 = a6 + bflo(sv.w) * d2 + bB.z;
        float r7 = a7 + bfhi(sv.w) * d2 + bB.w;
        if (relu) {
            r0 = fmaxf(r0, 0.f); r1 = fmaxf(r1, 0.f); r2 = fmaxf(r2, 0.f); r3 = fmaxf(r3, 0.f);
            r4 = fmaxf(r4, 0.f); r5 = fmaxf(r5, 0.f); r6 = fmaxf(r6, 0.f); r7 = fmaxf(r7, 0.f);
        }
        uint4 o;
        o.x = packbf(r0, r1); o.y = packbf(r2, r3);
        o.z = packbf(r4, r5); o.w = packbf(r6, r7);
        *(uint4*)(out + ((unsigned)node << 6) + (h8 << 3)) = o;
    }
}

extern "C" void kernel_launch(void* const* d_in, const int* in_sizes, int n_in,
                              void* d_out, int out_size, void* d_ws, size_t ws_size,
                              hipStream_t stream) {
    const float* x  = (const float*)d_in[0];
    const int*   ei = (const int*)d_in[1];   // [2][E] int32
    const float* W1 = (const float*)d_in[2];
    const float* b1 = (const float*)d_in[3];
    const float* W2 = (const float*)d_in[4];
    const float* b2 = (const float*)d_in[5];
    const float* Wl = (const float*)d_in[6];
    const float* bl = (const float*)d_in[7];
    float* out = (float*)d_out;

    const int n = in_sizes[0] / FEAT;   // 100000  (n < 131072: 196 buckets)
    const int E = in_sizes[1] / 2;      // 1200000
    const int* src = ei;
    const int* dst = ei + E;

    const int B = 256;
    const int nblocks = (n + B - 1) / B;
    const int NB = (n + 511) >> 9;            // 196 buckets
    const int pblocks = (E + 4095) / 4096;    // 293 partition blocks
    const int agg_blocks  = (n + 3) / 4;
    const int gemm_blocks = (n + 63) / 64;

    char* w = (char*)d_ws;
    int*   bcnt     = (int*)w;              w += 256 * 4;
    int*   bbase    = (int*)w;              w += 260 * 4;
    int*   bcur     = (int*)w;              w += 256 * 4;
    int*   blockSum = (int*)w;              w += 512 * 4;
    int*   cnt      = (int*)w;              w += (size_t)n * 4;
    int*   offs     = (int*)w;              w += ((size_t)n + 4) * 4;
    float* dinv     = (float*)w;            w += (size_t)n * 4;
    w = (char*)(((uintptr_t)w + 15) & ~(uintptr_t)15);
    unsigned* pass1 = (unsigned*)w;         w += (size_t)E * 4;
    int2*  edata    = (int2*)w;             w += (size_t)E * 8;
    unsigned short* bufA = (unsigned short*)w;  w += (size_t)n * FEAT * 2;  // h1 / h3
    unsigned short* bufB = (unsigned short*)w;                              // h2 / t

    // ---- CSR build via bucketed counting sort ----
    hipMemsetAsync(bcnt, 0, 256 * 4, stream);
    k_bhist<<<dim3(256), dim3(B), 0, stream>>>(dst, bcnt, E);
    k_bscan<<<dim3(1), dim3(B), 0, stream>>>(bcnt, bbase, bcur);
    k_part<<<dim3(pblocks), dim3(B), 0, stream>>>(src, dst, bcur, pass1, E);
    k_nhist<<<dim3(NB), dim3(B), 0, stream>>>(pass1, bbase, cnt, n);
    k_scan1<<<dim3(nblocks), dim3(B), 0, stream>>>(cnt, offs, blockSum, dinv, n);
    k_scan2<<<dim3(1), dim3(512), 0, stream>>>(blockSum, nblocks);
    k_scan3<<<dim3(nblocks), dim3(B), 0, stream>>>(offs, blockSum, n, E);
    k_fscatter<<<dim3(NB), dim3(B), 0, stream>>>(pass1, bbase, offs, dinv, edata);

    // ---- layer 1 ----
    k_gemm64t<false, false><<<dim3(gemm_blocks), dim3(B), 0, stream>>>(x, W1, nullptr, bufA, n);
    k_agg<<<dim3(agg_blocks), dim3(B), 0, stream>>>(offs, edata, bufA, b1, bufB, n, 1);

    // ---- layer 2 ----
    k_gemm64t<true, false><<<dim3(gemm_blocks), dim3(B), 0, stream>>>(bufB, W2, nullptr, bufA, n);
    k_agg<<<dim3(agg_blocks), dim3(B), 0, stream>>>(offs, edata, bufA, b2, bufB, n, 0);

    // ---- final linear ----
    k_gemm64t<true, true><<<dim3(gemm_blocks), dim3(B), 0, stream>>>(bufB, Wl, bl, out, n);
}

// Round 7
// 276.466 us; speedup vs baseline: 1.9073x; 1.2565x over previous
//
#include <hip/hip_runtime.h>

// 2-layer GCN, N=100000, E=1200000, dims 64, fp32 in/out.
//
// R7: replace the VALU GEMM (47us, VGPR 144, 8% occupancy, latency-stalled)
// with an MFMA GEMM: v_mfma_f32_16x16x32_bf16, one wave = 16-row tile =
// 4 col-tiles x 2 K-steps = 8 MFMA. W pre-packed once into B-fragment lane
// layout (B[k][n]: n=lane&15, k=(lane>>4)*8+j) -> 8x16B register-resident
// fragments per wave; A-fragments 16B/lane direct from global. Zero LDS.
// C/D: col=lane&15, row=(lane>>4)*4+reg. CSR build + k_agg unchanged (R6).

#define FEAT 64

typedef __attribute__((ext_vector_type(8))) short bf16x8;
typedef __attribute__((ext_vector_type(4))) float f32x4;
union BF8 { bf16x8 v; unsigned short u[8]; uint4 q; };

__device__ __forceinline__ unsigned short f2bf(float f) {
    unsigned u = __float_as_uint(f);
    return (unsigned short)((u + 0x7FFFu + ((u >> 16) & 1u)) >> 16);   // RNE
}
__device__ __forceinline__ float bf2f(unsigned short h) {
    return __uint_as_float(((unsigned)h) << 16);
}
__device__ __forceinline__ float bflo(unsigned u) { return __uint_as_float(u << 16); }
__device__ __forceinline__ float bfhi(unsigned u) { return __uint_as_float(u & 0xFFFF0000u); }
__device__ __forceinline__ unsigned packbf(float a, float b) {
    return (unsigned)f2bf(a) | ((unsigned)f2bf(b) << 16);
}

// ---- A: bucket histogram (bucket = dst >> 9) ----
__global__ void __launch_bounds__(256)
k_bhist(const int* __restrict__ dst, int* __restrict__ bcnt, int E) {
    __shared__ int h[256];
    int tid = threadIdx.x;
    h[tid] = 0;
    __syncthreads();
    int stride = gridDim.x * 256;
    for (int e = blockIdx.x * 256 + tid; e < E; e += stride)
        atomicAdd(&h[dst[e] >> 9], 1);
    __syncthreads();
    if (h[tid]) atomicAdd(&bcnt[tid], h[tid]);
}

// ---- B: exclusive scan of 256 bucket counts -> bbase (257 wide) + bcur ----
__global__ void k_bscan(const int* __restrict__ bcnt, int* __restrict__ bbase,
                        int* __restrict__ bcur) {
    __shared__ int s[256];
    int t = threadIdx.x;
    int v = bcnt[t];
    s[t] = v;
    __syncthreads();
    for (int off = 1; off < 256; off <<= 1) {
        int x = (t >= off) ? s[t - off] : 0;
        __syncthreads();
        s[t] += x;
        __syncthreads();
    }
    int ex = s[t] - v;
    bbase[t] = ex;
    bcur[t] = ex;
    if (t == 255) bbase[256] = s[255];
}

// ---- C: partition edges into buckets, packed (src<<9 | dst&511) ----
__global__ void __launch_bounds__(256)
k_part(const int* __restrict__ src, const int* __restrict__ dst,
       int* __restrict__ bcur, unsigned* __restrict__ pass1, int E) {
    __shared__ unsigned pk[4096];
    __shared__ unsigned char bk[4096];
    __shared__ int h[256];
    __shared__ int cur[256];
    int tid = threadIdx.x;
    h[tid] = 0;
    __syncthreads();
    int base = blockIdx.x * 4096;
#pragma unroll
    for (int i = 0; i < 16; ++i) {
        int li = i * 256 + tid;
        int e = base + li;
        if (e < E) {
            int s = src[e], d = dst[e];
            int b = d >> 9;
            pk[li] = ((unsigned)s << 9) | ((unsigned)d & 511u);
            bk[li] = (unsigned char)b;
            atomicAdd(&h[b], 1);
        } else {
            bk[li] = 255;
            pk[li] = 0xFFFFFFFFu;
        }
    }
    __syncthreads();
    {
        int c = h[tid];
        int run = c ? atomicAdd(&bcur[tid], c) : 0;
        cur[tid] = run;
    }
    __syncthreads();
#pragma unroll
    for (int i = 0; i < 16; ++i) {
        int li = i * 256 + tid;
        int e = base + li;
        if (e < E) {
            int b = bk[li];
            int pos = atomicAdd(&cur[b], 1);
            pass1[pos] = pk[li];
        }
    }
}

// ---- D1: per-bucket node histogram -> cnt ----
__global__ void __launch_bounds__(256)
k_nhist(const unsigned* __restrict__ pass1, const int* __restrict__ bbase,
        int* __restrict__ cnt, int n) {
    __shared__ int h[512];
    int tid = threadIdx.x;
    h[tid] = 0; h[tid + 256] = 0;
    __syncthreads();
    int b = blockIdx.x;
    int beg = bbase[b], end = bbase[b + 1];
    for (int j = beg + tid; j < end; j += 256)
        atomicAdd(&h[pass1[j] & 511u], 1);
    __syncthreads();
    int nb = b << 9;
#pragma unroll
    for (int q = 0; q < 2; ++q) {
        int t2 = tid + q * 256;
        int node = nb + t2;
        if (node < n) cnt[node] = h[t2];
    }
}

// ---- scan over cnt (offs) + fused dinv ----
__global__ void k_scan1(const int* __restrict__ cnt, int* __restrict__ partial,
                        int* __restrict__ blockSum, float* __restrict__ dinv, int n) {
    __shared__ int s[256];
    int t = threadIdx.x;
    int i = blockIdx.x * 256 + t;
    int v = (i < n) ? cnt[i] : 0;
    if (i < n) dinv[i] = rsqrtf((float)v + 1.0f);
    s[t] = v;
    __syncthreads();
    for (int off = 1; off < 256; off <<= 1) {
        int x = (t >= off) ? s[t - off] : 0;
        __syncthreads();
        s[t] += x;
        __syncthreads();
    }
    if (i < n) partial[i] = s[t] - v;
    if (t == 255) blockSum[blockIdx.x] = s[255];
}

__global__ void k_scan2(int* __restrict__ blockSum, int nb) {
    __shared__ int s[512];
    int t = threadIdx.x;
    int v = (t < nb) ? blockSum[t] : 0;
    s[t] = v;
    __syncthreads();
    for (int off = 1; off < 512; off <<= 1) {
        int x = (t >= off) ? s[t - off] : 0;
        __syncthreads();
        s[t] += x;
        __syncthreads();
    }
    if (t < nb) blockSum[t] = s[t] - v;
}

__global__ void k_scan3(int* __restrict__ offs, const int* __restrict__ blockSum,
                        int n, int E) {
    int i = blockIdx.x * 256 + threadIdx.x;
    if (i < n) offs[i] += blockSum[blockIdx.x];
    if (i == 0) offs[n] = E;
}

// ---- D2: per-bucket final scatter; ranks via LDS, edata = (src, norm) ----
__global__ void __launch_bounds__(256)
k_fscatter(const unsigned* __restrict__ pass1, const int* __restrict__ bbase,
           const int* __restrict__ offs, const float* __restrict__ dinv,
           int2* __restrict__ edata) {
    __shared__ int cur[512];
    int tid = threadIdx.x;
    cur[tid] = 0; cur[tid + 256] = 0;
    __syncthreads();
    int b = blockIdx.x;
    int beg = bbase[b], end = bbase[b + 1];
    int nb = b << 9;
    for (int j = beg + tid; j < end; j += 256) {
        unsigned u = pass1[j];
        int loc = (int)(u & 511u);
        int s = (int)(u >> 9);
        int node = nb + loc;
        int r = atomicAdd(&cur[loc], 1);
        int pos = offs[node] + r;
        edata[pos] = make_int2(s, __float_as_int(dinv[s] * dinv[node]));
    }
}

// ---- W pre-pack into MFMA B-fragment layout (bf16), 3 matrices ----
// P[b][i], i = ((c*2+s)*64 + lane)*8 + j  <=  W[k][col], k=s*32+(lane>>4)*8+j,
// col = c*16 + (lane&15)
__global__ void k_prepw(const float* __restrict__ W1, const float* __restrict__ W2,
                        const float* __restrict__ Wl, unsigned short* __restrict__ P) {
    const float* W = (blockIdx.x == 0) ? W1 : (blockIdx.x == 1) ? W2 : Wl;
    unsigned short* p = P + blockIdx.x * 4096;
    for (int i = threadIdx.x; i < 4096; i += 256) {
        int c = i >> 10, s = (i >> 9) & 1, l = (i >> 3) & 63, j = i & 7;
        int k = s * 32 + ((l >> 4) << 3) + j;
        int col = (c << 4) + (l & 15);
        p[i] = f2bf(W[k * 64 + col]);
    }
}

// ---- MFMA GEMM: H[n,64] = X[n,64] @ W[64,64] (+bias if OUT_F32) ----
// One wave per 16-row tile; 8 MFMA (4 col-tiles x 2 K-steps); zero LDS.
template <bool IN_BF16, bool OUT_F32>
__global__ void __launch_bounds__(256)
k_gemm_mfma(const void* __restrict__ Xv, const unsigned short* __restrict__ Wpk,
            const float* __restrict__ bias, void* __restrict__ Hv, int n) {
    int lane = threadIdx.x & 63;
    int wid = (blockIdx.x << 2) + (threadIdx.x >> 6);
    int nw = gridDim.x << 2;
    int T = (n + 15) >> 4;
    BF8 bfr[8];
    const uint4* wp = (const uint4*)Wpk;
#pragma unroll
    for (int f = 0; f < 8; ++f) bfr[f].q = wp[f * 64 + lane];
    int mrow = lane & 15, kq = lane >> 4, colb = lane & 15;
    float bb0 = 0.f, bb1 = 0.f, bb2 = 0.f, bb3 = 0.f;
    if (OUT_F32) {
        bb0 = bias[colb]; bb1 = bias[16 + colb];
        bb2 = bias[32 + colb]; bb3 = bias[48 + colb];
    }
    for (int t = wid; t < T; t += nw) {
        int rb = t << 4;
        int row = rb + mrow;
        bool ok = row < n;
        BF8 a0, a1;
        if (IN_BF16) {
            const uint4* xr = (const uint4*)((const unsigned short*)Xv + ((unsigned)row << 6));
            a0.q = ok ? xr[kq]     : make_uint4(0, 0, 0, 0);
            a1.q = ok ? xr[kq + 4] : make_uint4(0, 0, 0, 0);
        } else {
            const float4* xr = (const float4*)((const float*)Xv + ((unsigned)row << 6));
            float4 z = make_float4(0.f, 0.f, 0.f, 0.f);
            float4 p0 = ok ? xr[kq * 2]     : z;
            float4 p1 = ok ? xr[kq * 2 + 1] : z;
            float4 p2 = ok ? xr[8 + kq * 2] : z;
            float4 p3 = ok ? xr[8 + kq * 2 + 1] : z;
            a0.u[0] = f2bf(p0.x); a0.u[1] = f2bf(p0.y); a0.u[2] = f2bf(p0.z); a0.u[3] = f2bf(p0.w);
            a0.u[4] = f2bf(p1.x); a0.u[5] = f2bf(p1.y); a0.u[6] = f2bf(p1.z); a0.u[7] = f2bf(p1.w);
            a1.u[0] = f2bf(p2.x); a1.u[1] = f2bf(p2.y); a1.u[2] = f2bf(p2.z); a1.u[3] = f2bf(p2.w);
            a1.u[4] = f2bf(p3.x); a1.u[5] = f2bf(p3.y); a1.u[6] = f2bf(p3.z); a1.u[7] = f2bf(p3.w);
        }
        f32x4 acc0 = {0.f, 0.f, 0.f, 0.f}, acc1 = acc0, acc2 = acc0, acc3 = acc0;
        acc0 = __builtin_amdgcn_mfma_f32_16x16x32_bf16(a0.v, bfr[0].v, acc0, 0, 0, 0);
        acc0 = __builtin_amdgcn_mfma_f32_16x16x32_bf16(a1.v, bfr[1].v, acc0, 0, 0, 0);
        acc1 = __builtin_amdgcn_mfma_f32_16x16x32_bf16(a0.v, bfr[2].v, acc1, 0, 0, 0);
        acc1 = __builtin_amdgcn_mfma_f32_16x16x32_bf16(a1.v, bfr[3].v, acc1, 0, 0, 0);
        acc2 = __builtin_amdgcn_mfma_f32_16x16x32_bf16(a0.v, bfr[4].v, acc2, 0, 0, 0);
        acc2 = __builtin_amdgcn_mfma_f32_16x16x32_bf16(a1.v, bfr[5].v, acc2, 0, 0, 0);
        acc3 = __builtin_amdgcn_mfma_f32_16x16x32_bf16(a0.v, bfr[6].v, acc3, 0, 0, 0);
        acc3 = __builtin_amdgcn_mfma_f32_16x16x32_bf16(a1.v, bfr[7].v, acc3, 0, 0, 0);
        int rowb = rb + (kq << 2);
        if (OUT_F32) {
            float* O = (float*)Hv;
#pragma unroll
            for (int i = 0; i < 4; ++i) {
                if (rowb + i >= n) break;
                unsigned ro = (unsigned)(rowb + i) << 6;
                O[ro + colb]      = acc0[i] + bb0;
                O[ro + 16 + colb] = acc1[i] + bb1;
                O[ro + 32 + colb] = acc2[i] + bb2;
                O[ro + 48 + colb] = acc3[i] + bb3;
            }
        } else {
            unsigned short* O = (unsigned short*)Hv;
#pragma unroll
            for (int i = 0; i < 4; ++i) {
                if (rowb + i >= n) break;
                unsigned ro = (unsigned)(rowb + i) << 6;
                O[ro + colb]      = f2bf(acc0[i]);
                O[ro + 16 + colb] = f2bf(acc1[i]);
                O[ro + 32 + colb] = f2bf(acc2[i]);
                O[ro + 48 + colb] = f2bf(acc3[i]);
            }
        }
    }
}

// ---- aggregation (unchanged from R6) ----
__global__ void __launch_bounds__(256)
k_agg(const int* __restrict__ offs, const int2* __restrict__ edata,
      const unsigned short* __restrict__ H, const float* __restrict__ bias,
      unsigned short* __restrict__ out, int n, int relu) {
    int node = blockIdx.x * 4 + (threadIdx.x >> 6);
    if (node >= n) return;
    int lane = threadIdx.x & 63;
    int g = lane >> 3, h8 = lane & 7;
    int beg = offs[node], end = offs[node + 1];
    float a0 = 0.f, a1 = 0.f, a2 = 0.f, a3 = 0.f, a4 = 0.f, a5 = 0.f, a6 = 0.f, a7 = 0.f;
    int j = beg + g;
    if (j < end) {
        int2 e = edata[j];
        for (;;) {
            int jn = j + 8;
            bool more = jn < end;
            int2 en = more ? edata[jn] : make_int2(0, 0);   // prefetch
            float nn = __int_as_float(e.y);
            uint4 hv = *(const uint4*)(H + ((unsigned)e.x << 6) + (h8 << 3));
            a0 += bflo(hv.x) * nn; a1 += bfhi(hv.x) * nn;
            a2 += bflo(hv.y) * nn; a3 += bfhi(hv.y) * nn;
            a4 += bflo(hv.z) * nn; a5 += bfhi(hv.z) * nn;
            a6 += bflo(hv.w) * nn; a7 += bfhi(hv.w) * nn;
            if (!more) break;
            e = en; j = jn;
        }
    }
#pragma unroll
    for (int m = 8; m < 64; m <<= 1) {
        a0 += __shfl_xor(a0, m); a1 += __shfl_xor(a1, m);
        a2 += __shfl_xor(a2, m); a3 += __shfl_xor(a3, m);
        a4 += __shfl_xor(a4, m); a5 += __shfl_xor(a5, m);
        a6 += __shfl_xor(a6, m); a7 += __shfl_xor(a7, m);
    }
    if (g == 0) {
        float d2 = 1.0f / (float)(end - beg + 1);
        uint4 sv = *(const uint4*)(H + ((unsigned)node << 6) + (h8 << 3));
        const float4* b4 = (const float4*)bias;
        float4 bA = b4[h8 * 2], bB = b4[h8 * 2 + 1];
        float r0 = a0 + bflo(sv.x) * d2 + bA.x;
        float r1 = a1 + bfhi(sv.x) * d2 + bA.y;
        float r2 = a2 + bflo(sv.y) * d2 + bA.z;
        float r3 = a3 + bfhi(sv.y) * d2 + bA.w;
        float r4 = a4 + bflo(sv.z) * d2 + bB.x;
        float r5 = a5 + bfhi(sv.z) * d2 + bB.y;
        float r6 = a6 + bflo(sv.w) * d2 + bB.z;
        float r7 = a7 + bfhi(sv.w) * d2 + bB.w;
        if (relu) {
            r0 = fmaxf(r0, 0.f); r1 = fmaxf(r1, 0.f); r2 = fmaxf(r2, 0.f); r3 = fmaxf(r3, 0.f);
            r4 = fmaxf(r4, 0.f); r5 = fmaxf(r5, 0.f); r6 = fmaxf(r6, 0.f); r7 = fmaxf(r7, 0.f);
        }
        uint4 o;
        o.x = packbf(r0, r1); o.y = packbf(r2, r3);
        o.z = packbf(r4, r5); o.w = packbf(r6, r7);
        *(uint4*)(out + ((unsigned)node << 6) + (h8 << 3)) = o;
    }
}

extern "C" void kernel_launch(void* const* d_in, const int* in_sizes, int n_in,
                              void* d_out, int out_size, void* d_ws, size_t ws_size,
                              hipStream_t stream) {
    const float* x  = (const float*)d_in[0];
    const int*   ei = (const int*)d_in[1];   // [2][E] int32
    const float* W1 = (const float*)d_in[2];
    const float* b1 = (const float*)d_in[3];
    const float* W2 = (const float*)d_in[4];
    const float* b2 = (const float*)d_in[5];
    const float* Wl = (const float*)d_in[6];
    const float* bl = (const float*)d_in[7];
    float* out = (float*)d_out;

    const int n = in_sizes[0] / FEAT;   // 100000
    const int E = in_sizes[1] / 2;      // 1200000
    const int* src = ei;
    const int* dst = ei + E;

    const int B = 256;
    const int nblocks = (n + B - 1) / B;
    const int NB = (n + 511) >> 9;
    const int pblocks = (E + 4095) / 4096;
    const int agg_blocks  = (n + 3) / 4;
    const int T = (n + 15) / 16;
    const int gemm_blocks = (T + 3) / 4;    // 1 tile per wave

    char* w = (char*)d_ws;
    int*   bcnt     = (int*)w;              w += 256 * 4;
    int*   bbase    = (int*)w;              w += 260 * 4;
    int*   bcur     = (int*)w;              w += 256 * 4;
    int*   blockSum = (int*)w;              w += 512 * 4;
    int*   cnt      = (int*)w;              w += (size_t)n * 4;
    int*   offs     = (int*)w;              w += ((size_t)n + 4) * 4;
    float* dinv     = (float*)w;            w += (size_t)n * 4;
    w = (char*)(((uintptr_t)w + 15) & ~(uintptr_t)15);
    unsigned short* Wpk = (unsigned short*)w;  w += 3 * 4096 * 2;
    unsigned* pass1 = (unsigned*)w;         w += (size_t)E * 4;
    int2*  edata    = (int2*)w;             w += (size_t)E * 8;
    unsigned short* bufA = (unsigned short*)w;  w += (size_t)n * FEAT * 2;  // h1 / h3
    unsigned short* bufB = (unsigned short*)w;                              // h2 / t

    // ---- W pre-pack (independent of edge data) ----
    k_prepw<<<dim3(3), dim3(B), 0, stream>>>(W1, W2, Wl, Wpk);

    // ---- CSR build via bucketed counting sort ----
    hipMemsetAsync(bcnt, 0, 256 * 4, stream);
    k_bhist<<<dim3(256), dim3(B), 0, stream>>>(dst, bcnt, E);
    k_bscan<<<dim3(1), dim3(B), 0, stream>>>(bcnt, bbase, bcur);
    k_part<<<dim3(pblocks), dim3(B), 0, stream>>>(src, dst, bcur, pass1, E);
    k_nhist<<<dim3(NB), dim3(B), 0, stream>>>(pass1, bbase, cnt, n);
    k_scan1<<<dim3(nblocks), dim3(B), 0, stream>>>(cnt, offs, blockSum, dinv, n);
    k_scan2<<<dim3(1), dim3(512), 0, stream>>>(blockSum, nblocks);
    k_scan3<<<dim3(nblocks), dim3(B), 0, stream>>>(offs, blockSum, n, E);
    k_fscatter<<<dim3(NB), dim3(B), 0, stream>>>(pass1, bbase, offs, dinv, edata);

    // ---- layer 1 ----
    k_gemm_mfma<false, false><<<dim3(gemm_blocks), dim3(B), 0, stream>>>(x, Wpk, nullptr, bufA, n);
    k_agg<<<dim3(agg_blocks), dim3(B), 0, stream>>>(offs, edata, bufA, b1, bufB, n, 1);

    // ---- layer 2 ----
    k_gemm_mfma<true, false><<<dim3(gemm_blocks), dim3(B), 0, stream>>>(bufB, Wpk + 4096, nullptr, bufA, n);
    k_agg<<<dim3(agg_blocks), dim3(B), 0, stream>>>(offs, edata, bufA, b2, bufB, n, 0);

    // ---- final linear ----
    k_gemm_mfma<true, true><<<dim3(gemm_blocks), dim3(B), 0, stream>>>(bufB, Wpk + 8192, bl, out, n);
}

// Round 8
// 271.862 us; speedup vs baseline: 1.9396x; 1.0169x over previous
//
#include <hip/hip_runtime.h>

// 2-layer GCN, N=100000, E=1200000, dims 64, fp32 in/out.
//
// R8: (1) agg restructured 8x8 -> 4 slots x 16 lanes (8B loads): 4 accs,
// 2-stage shfl reduce (was 8 accs x 3 stages = ~96cyc), half the epilogue.
// (2) CSR tail merged: per-bucket k_csr does hist + LDS scan + offs/dinv +
// scatter (global base = bbase[b], so no global scan kernels). esrc is 4B
// (src only); agg re-gathers dinv[s] (L2-hot broadcast). bcnt zeroing
// folded into k_prepw. 15 -> 10 launches. MFMA GEMM unchanged (R7).

#define FEAT 64

typedef __attribute__((ext_vector_type(8))) short bf16x8;
typedef __attribute__((ext_vector_type(4))) float f32x4;
union BF8 { bf16x8 v; unsigned short u[8]; uint4 q; };

__device__ __forceinline__ unsigned short f2bf(float f) {
    unsigned u = __float_as_uint(f);
    return (unsigned short)((u + 0x7FFFu + ((u >> 16) & 1u)) >> 16);   // RNE
}
__device__ __forceinline__ float bf2f(unsigned short h) {
    return __uint_as_float(((unsigned)h) << 16);
}
__device__ __forceinline__ float bflo(unsigned u) { return __uint_as_float(u << 16); }
__device__ __forceinline__ float bfhi(unsigned u) { return __uint_as_float(u & 0xFFFF0000u); }
__device__ __forceinline__ unsigned packbf(float a, float b) {
    return (unsigned)f2bf(a) | ((unsigned)f2bf(b) << 16);
}

// ---- W pre-pack into MFMA B-fragment layout (blocks 0-2) + zero bcnt (block 3) ----
__global__ void k_prepw(const float* __restrict__ W1, const float* __restrict__ W2,
                        const float* __restrict__ Wl, unsigned short* __restrict__ P,
                        int* __restrict__ bcnt) {
    if (blockIdx.x == 3) {
        if (threadIdx.x < 256) bcnt[threadIdx.x] = 0;
        return;
    }
    const float* W = (blockIdx.x == 0) ? W1 : (blockIdx.x == 1) ? W2 : Wl;
    unsigned short* p = P + blockIdx.x * 4096;
    for (int i = threadIdx.x; i < 4096; i += 256) {
        int c = i >> 10, s = (i >> 9) & 1, l = (i >> 3) & 63, j = i & 7;
        int k = s * 32 + ((l >> 4) << 3) + j;
        int col = (c << 4) + (l & 15);
        p[i] = f2bf(W[k * 64 + col]);
    }
}

// ---- bucket histogram (bucket = dst >> 9) ----
__global__ void __launch_bounds__(256)
k_bhist(const int* __restrict__ dst, int* __restrict__ bcnt, int E) {
    __shared__ int h[256];
    int tid = threadIdx.x;
    h[tid] = 0;
    __syncthreads();
    int stride = gridDim.x * 256;
    for (int e = blockIdx.x * 256 + tid; e < E; e += stride)
        atomicAdd(&h[dst[e] >> 9], 1);
    __syncthreads();
    if (h[tid]) atomicAdd(&bcnt[tid], h[tid]);
}

// ---- exclusive scan of 256 bucket counts -> bbase (257 wide) + bcur ----
__global__ void k_bscan(const int* __restrict__ bcnt, int* __restrict__ bbase,
                        int* __restrict__ bcur) {
    __shared__ int s[256];
    int t = threadIdx.x;
    int v = bcnt[t];
    s[t] = v;
    __syncthreads();
    for (int off = 1; off < 256; off <<= 1) {
        int x = (t >= off) ? s[t - off] : 0;
        __syncthreads();
        s[t] += x;
        __syncthreads();
    }
    int ex = s[t] - v;
    bbase[t] = ex;
    bcur[t] = ex;
    if (t == 255) bbase[256] = s[255];
}

// ---- partition edges into buckets, packed (src<<9 | dst&511) ----
__global__ void __launch_bounds__(256)
k_part(const int* __restrict__ src, const int* __restrict__ dst,
       int* __restrict__ bcur, unsigned* __restrict__ pass1, int E) {
    __shared__ unsigned pk[4096];
    __shared__ unsigned char bk[4096];
    __shared__ int h[256];
    __shared__ int cur[256];
    int tid = threadIdx.x;
    h[tid] = 0;
    __syncthreads();
    int base = blockIdx.x * 4096;
#pragma unroll
    for (int i = 0; i < 16; ++i) {
        int li = i * 256 + tid;
        int e = base + li;
        if (e < E) {
            int s = src[e], d = dst[e];
            int b = d >> 9;
            pk[li] = ((unsigned)s << 9) | ((unsigned)d & 511u);
            bk[li] = (unsigned char)b;
            atomicAdd(&h[b], 1);
        } else {
            bk[li] = 255;
            pk[li] = 0xFFFFFFFFu;
        }
    }
    __syncthreads();
    {
        int c = h[tid];
        int run = c ? atomicAdd(&bcur[tid], c) : 0;
        cur[tid] = run;
    }
    __syncthreads();
#pragma unroll
    for (int i = 0; i < 16; ++i) {
        int li = i * 256 + tid;
        int e = base + li;
        if (e < E) {
            int b = bk[li];
            int pos = atomicAdd(&cur[b], 1);
            pass1[pos] = pk[li];
        }
    }
}

// ---- per-bucket CSR finish: node hist -> LDS scan -> offs/dinv -> scatter ----
__global__ void __launch_bounds__(512)
k_csr(const unsigned* __restrict__ pass1, const int* __restrict__ bbase,
      int* __restrict__ offs, float* __restrict__ dinv, int* __restrict__ esrc,
      int n, int E) {
    __shared__ int hist[512];
    __shared__ int cur[512];
    int tid = threadIdx.x;
    int b = blockIdx.x;
    hist[tid] = 0;
    __syncthreads();
    int beg = bbase[b], end = bbase[b + 1];
    for (int j = beg + tid; j < end; j += 512)
        atomicAdd(&hist[pass1[j] & 511u], 1);
    __syncthreads();
    int v = hist[tid];
    for (int off = 1; off < 512; off <<= 1) {        // inclusive scan
        int x = (tid >= off) ? hist[tid - off] : 0;
        __syncthreads();
        hist[tid] += x;
        __syncthreads();
    }
    int excl = hist[tid] - v;
    int node = (b << 9) + tid;
    if (node < n) {
        offs[node] = beg + excl;
        dinv[node] = rsqrtf((float)v + 1.0f);
    }
    cur[tid] = excl;
    if (b == 0 && tid == 0) offs[n] = E;
    __syncthreads();
    for (int j = beg + tid; j < end; j += 512) {
        unsigned u = pass1[j];
        int loc = (int)(u & 511u);
        int r = atomicAdd(&cur[loc], 1);
        esrc[beg + r] = (int)(u >> 9);
    }
}

// ---- MFMA GEMM: H[n,64] = X[n,64] @ W[64,64] (+bias if OUT_F32) ----
template <bool IN_BF16, bool OUT_F32>
__global__ void __launch_bounds__(256)
k_gemm_mfma(const void* __restrict__ Xv, const unsigned short* __restrict__ Wpk,
            const float* __restrict__ bias, void* __restrict__ Hv, int n) {
    int lane = threadIdx.x & 63;
    int wid = (blockIdx.x << 2) + (threadIdx.x >> 6);
    int nw = gridDim.x << 2;
    int T = (n + 15) >> 4;
    BF8 bfr[8];
    const uint4* wp = (const uint4*)Wpk;
#pragma unroll
    for (int f = 0; f < 8; ++f) bfr[f].q = wp[f * 64 + lane];
    int mrow = lane & 15, kq = lane >> 4, colb = lane & 15;
    float bb0 = 0.f, bb1 = 0.f, bb2 = 0.f, bb3 = 0.f;
    if (OUT_F32) {
        bb0 = bias[colb]; bb1 = bias[16 + colb];
        bb2 = bias[32 + colb]; bb3 = bias[48 + colb];
    }
    for (int t = wid; t < T; t += nw) {
        int rb = t << 4;
        int row = rb + mrow;
        bool ok = row < n;
        BF8 a0, a1;
        if (IN_BF16) {
            const uint4* xr = (const uint4*)((const unsigned short*)Xv + ((unsigned)row << 6));
            a0.q = ok ? xr[kq]     : make_uint4(0, 0, 0, 0);
            a1.q = ok ? xr[kq + 4] : make_uint4(0, 0, 0, 0);
        } else {
            const float4* xr = (const float4*)((const float*)Xv + ((unsigned)row << 6));
            float4 z = make_float4(0.f, 0.f, 0.f, 0.f);
            float4 p0 = ok ? xr[kq * 2]     : z;
            float4 p1 = ok ? xr[kq * 2 + 1] : z;
            float4 p2 = ok ? xr[8 + kq * 2] : z;
            float4 p3 = ok ? xr[8 + kq * 2 + 1] : z;
            a0.u[0] = f2bf(p0.x); a0.u[1] = f2bf(p0.y); a0.u[2] = f2bf(p0.z); a0.u[3] = f2bf(p0.w);
            a0.u[4] = f2bf(p1.x); a0.u[5] = f2bf(p1.y); a0.u[6] = f2bf(p1.z); a0.u[7] = f2bf(p1.w);
            a1.u[0] = f2bf(p2.x); a1.u[1] = f2bf(p2.y); a1.u[2] = f2bf(p2.z); a1.u[3] = f2bf(p2.w);
            a1.u[4] = f2bf(p3.x); a1.u[5] = f2bf(p3.y); a1.u[6] = f2bf(p3.z); a1.u[7] = f2bf(p3.w);
        }
        f32x4 acc0 = {0.f, 0.f, 0.f, 0.f}, acc1 = acc0, acc2 = acc0, acc3 = acc0;
        acc0 = __builtin_amdgcn_mfma_f32_16x16x32_bf16(a0.v, bfr[0].v, acc0, 0, 0, 0);
        acc0 = __builtin_amdgcn_mfma_f32_16x16x32_bf16(a1.v, bfr[1].v, acc0, 0, 0, 0);
        acc1 = __builtin_amdgcn_mfma_f32_16x16x32_bf16(a0.v, bfr[2].v, acc1, 0, 0, 0);
        acc1 = __builtin_amdgcn_mfma_f32_16x16x32_bf16(a1.v, bfr[3].v, acc1, 0, 0, 0);
        acc2 = __builtin_amdgcn_mfma_f32_16x16x32_bf16(a0.v, bfr[4].v, acc2, 0, 0, 0);
        acc2 = __builtin_amdgcn_mfma_f32_16x16x32_bf16(a1.v, bfr[5].v, acc2, 0, 0, 0);
        acc3 = __builtin_amdgcn_mfma_f32_16x16x32_bf16(a0.v, bfr[6].v, acc3, 0, 0, 0);
        acc3 = __builtin_amdgcn_mfma_f32_16x16x32_bf16(a1.v, bfr[7].v, acc3, 0, 0, 0);
        int rowb = rb + (kq << 2);
        if (OUT_F32) {
            float* O = (float*)Hv;
#pragma unroll
            for (int i = 0; i < 4; ++i) {
                if (rowb + i >= n) break;
                unsigned ro = (unsigned)(rowb + i) << 6;
                O[ro + colb]      = acc0[i] + bb0;
                O[ro + 16 + colb] = acc1[i] + bb1;
                O[ro + 32 + colb] = acc2[i] + bb2;
                O[ro + 48 + colb] = acc3[i] + bb3;
            }
        } else {
            unsigned short* O = (unsigned short*)Hv;
#pragma unroll
            for (int i = 0; i < 4; ++i) {
                if (rowb + i >= n) break;
                unsigned ro = (unsigned)(rowb + i) << 6;
                O[ro + colb]      = f2bf(acc0[i]);
                O[ro + 16 + colb] = f2bf(acc1[i]);
                O[ro + 32 + colb] = f2bf(acc2[i]);
                O[ro + 48 + colb] = f2bf(acc3[i]);
            }
        }
    }
}

// ---- aggregation: one wave/node, 4 edge-slots x 16 lanes x 8B gathers ----
__global__ void __launch_bounds__(256)
k_agg(const int* __restrict__ offs, const int* __restrict__ esrc,
      const float* __restrict__ dinv, const unsigned short* __restrict__ H,
      const float* __restrict__ bias, unsigned short* __restrict__ out,
      int n, int relu) {
    int node = blockIdx.x * 4 + (threadIdx.x >> 6);
    if (node >= n) return;
    int lane = threadIdx.x & 63;
    int g = lane >> 4, fl = lane & 15;
    int beg = offs[node], end = offs[node + 1];
    float dd = dinv[node];
    float a0 = 0.f, a1 = 0.f, a2 = 0.f, a3 = 0.f;
    int j = beg + g;
    if (j < end) {
        int s = esrc[j];
        for (;;) {
            int jn = j + 4;
            bool more = jn < end;
            int sn = more ? esrc[jn] : 0;               // prefetch next index
            float nn = dinv[s] * dd;
            uint2 hv = *(const uint2*)(H + ((unsigned)s << 6) + (fl << 2));
            a0 += bflo(hv.x) * nn; a1 += bfhi(hv.x) * nn;
            a2 += bflo(hv.y) * nn; a3 += bfhi(hv.y) * nn;
            if (!more) break;
            s = sn; j = jn;
        }
    }
    a0 += __shfl_xor(a0, 16); a1 += __shfl_xor(a1, 16);
    a2 += __shfl_xor(a2, 16); a3 += __shfl_xor(a3, 16);
    a0 += __shfl_xor(a0, 32); a1 += __shfl_xor(a1, 32);
    a2 += __shfl_xor(a2, 32); a3 += __shfl_xor(a3, 32);
    if (g == 0) {
        float d2 = dd * dd;
        uint2 sv = *(const uint2*)(H + ((unsigned)node << 6) + (fl << 2));
        float4 bv = ((const float4*)bias)[fl];
        float r0 = a0 + bflo(sv.x) * d2 + bv.x;
        float r1 = a1 + bfhi(sv.x) * d2 + bv.y;
        float r2 = a2 + bflo(sv.y) * d2 + bv.z;
        float r3 = a3 + bfhi(sv.y) * d2 + bv.w;
        if (relu) {
            r0 = fmaxf(r0, 0.f); r1 = fmaxf(r1, 0.f);
            r2 = fmaxf(r2, 0.f); r3 = fmaxf(r3, 0.f);
        }
        uint2 o;
        o.x = packbf(r0, r1); o.y = packbf(r2, r3);
        *(uint2*)(out + ((unsigned)node << 6) + (fl << 2)) = o;
    }
}

extern "C" void kernel_launch(void* const* d_in, const int* in_sizes, int n_in,
                              void* d_out, int out_size, void* d_ws, size_t ws_size,
                              hipStream_t stream) {
    const float* x  = (const float*)d_in[0];
    const int*   ei = (const int*)d_in[1];   // [2][E] int32
    const float* W1 = (const float*)d_in[2];
    const float* b1 = (const float*)d_in[3];
    const float* W2 = (const float*)d_in[4];
    const float* b2 = (const float*)d_in[5];
    const float* Wl = (const float*)d_in[6];
    const float* bl = (const float*)d_in[7];
    float* out = (float*)d_out;

    const int n = in_sizes[0] / FEAT;   // 100000
    const int E = in_sizes[1] / 2;      // 1200000
    const int* src = ei;
    const int* dst = ei + E;

    const int B = 256;
    const int NB = (n + 511) >> 9;            // 196 buckets
    const int pblocks = (E + 4095) / 4096;
    const int agg_blocks  = (n + 3) / 4;
    const int T = (n + 15) / 16;
    const int gemm_blocks = (T + 3) / 4;

    char* w = (char*)d_ws;
    int*   bcnt     = (int*)w;              w += 256 * 4;
    int*   bbase    = (int*)w;              w += 260 * 4;
    int*   bcur     = (int*)w;              w += 256 * 4;
    int*   offs     = (int*)w;              w += ((size_t)n + 4) * 4;
    float* dinv     = (float*)w;            w += (size_t)n * 4;
    w = (char*)(((uintptr_t)w + 15) & ~(uintptr_t)15);
    unsigned short* Wpk = (unsigned short*)w;  w += 3 * 4096 * 2;
    unsigned* pass1 = (unsigned*)w;         w += (size_t)E * 4;
    int*   esrc     = (int*)w;              w += (size_t)E * 4;
    unsigned short* bufA = (unsigned short*)w;  w += (size_t)n * FEAT * 2;  // h1 / h3
    unsigned short* bufB = (unsigned short*)w;                              // h2 / t

    // ---- prep: W pack + bcnt zero ----
    k_prepw<<<dim3(4), dim3(B), 0, stream>>>(W1, W2, Wl, Wpk, bcnt);

    // ---- CSR build ----
    k_bhist<<<dim3(256), dim3(B), 0, stream>>>(dst, bcnt, E);
    k_bscan<<<dim3(1), dim3(B), 0, stream>>>(bcnt, bbase, bcur);
    k_part<<<dim3(pblocks), dim3(B), 0, stream>>>(src, dst, bcur, pass1, E);
    k_csr<<<dim3(NB), dim3(512), 0, stream>>>(pass1, bbase, offs, dinv, esrc, n, E);

    // ---- layer 1 ----
    k_gemm_mfma<false, false><<<dim3(gemm_blocks), dim3(B), 0, stream>>>(x, Wpk, nullptr, bufA, n);
    k_agg<<<dim3(agg_blocks), dim3(B), 0, stream>>>(offs, esrc, dinv, bufA, b1, bufB, n, 1);

    // ---- layer 2 ----
    k_gemm_mfma<true, false><<<dim3(gemm_blocks), dim3(B), 0, stream>>>(bufB, Wpk + 4096, nullptr, bufA, n);
    k_agg<<<dim3(agg_blocks), dim3(B), 0, stream>>>(offs, esrc, dinv, bufA, b2, bufB, n, 0);

    // ---- final linear ----
    k_gemm_mfma<true, true><<<dim3(gemm_blocks), dim3(B), 0, stream>>>(bufB, Wpk + 8192, bl, out, n);
}

// Round 9
// 259.476 us; speedup vs baseline: 2.0322x; 1.0477x over previous
//
#include <hip/hip_runtime.h>

// 2-layer GCN, N=100000, E=1200000, dims 64, fp32 in/out.
//
// R9: fold dinv into H ("Hs = (X@W)*dinv[row]" in the GEMM epilogue).
// Then agg(d) = dinv[d]*(sum Hs[src] + Hs[d]) + b: NO per-edge norm, no
// dinv[s] gather (R8's regression), no 8B edata stream. Agg reverts to the
// proven 8 slots x 8 lanes x 16B shape with esrc-only prefetch. Merged
// k_csr (R8) kept — it could never produce cross-bucket norms anyway.
// MFMA GEMM (R7) + row-scale epilogue.

#define FEAT 64

typedef __attribute__((ext_vector_type(8))) short bf16x8;
typedef __attribute__((ext_vector_type(4))) float f32x4;
union BF8 { bf16x8 v; unsigned short u[8]; uint4 q; };

__device__ __forceinline__ unsigned short f2bf(float f) {
    unsigned u = __float_as_uint(f);
    return (unsigned short)((u + 0x7FFFu + ((u >> 16) & 1u)) >> 16);   // RNE
}
__device__ __forceinline__ float bf2f(unsigned short h) {
    return __uint_as_float(((unsigned)h) << 16);
}
__device__ __forceinline__ float bflo(unsigned u) { return __uint_as_float(u << 16); }
__device__ __forceinline__ float bfhi(unsigned u) { return __uint_as_float(u & 0xFFFF0000u); }
__device__ __forceinline__ unsigned packbf(float a, float b) {
    return (unsigned)f2bf(a) | ((unsigned)f2bf(b) << 16);
}

// ---- W pre-pack into MFMA B-fragment layout (blocks 0-2) + zero bcnt (block 3) ----
__global__ void k_prepw(const float* __restrict__ W1, const float* __restrict__ W2,
                        const float* __restrict__ Wl, unsigned short* __restrict__ P,
                        int* __restrict__ bcnt) {
    if (blockIdx.x == 3) {
        if (threadIdx.x < 256) bcnt[threadIdx.x] = 0;
        return;
    }
    const float* W = (blockIdx.x == 0) ? W1 : (blockIdx.x == 1) ? W2 : Wl;
    unsigned short* p = P + blockIdx.x * 4096;
    for (int i = threadIdx.x; i < 4096; i += 256) {
        int c = i >> 10, s = (i >> 9) & 1, l = (i >> 3) & 63, j = i & 7;
        int k = s * 32 + ((l >> 4) << 3) + j;
        int col = (c << 4) + (l & 15);
        p[i] = f2bf(W[k * 64 + col]);
    }
}

// ---- bucket histogram (bucket = dst >> 9) ----
__global__ void __launch_bounds__(256)
k_bhist(const int* __restrict__ dst, int* __restrict__ bcnt, int E) {
    __shared__ int h[256];
    int tid = threadIdx.x;
    h[tid] = 0;
    __syncthreads();
    int stride = gridDim.x * 256;
    for (int e = blockIdx.x * 256 + tid; e < E; e += stride)
        atomicAdd(&h[dst[e] >> 9], 1);
    __syncthreads();
    if (h[tid]) atomicAdd(&bcnt[tid], h[tid]);
}

// ---- exclusive scan of 256 bucket counts -> bbase (257 wide) + bcur ----
__global__ void k_bscan(const int* __restrict__ bcnt, int* __restrict__ bbase,
                        int* __restrict__ bcur) {
    __shared__ int s[256];
    int t = threadIdx.x;
    int v = bcnt[t];
    s[t] = v;
    __syncthreads();
    for (int off = 1; off < 256; off <<= 1) {
        int x = (t >= off) ? s[t - off] : 0;
        __syncthreads();
        s[t] += x;
        __syncthreads();
    }
    int ex = s[t] - v;
    bbase[t] = ex;
    bcur[t] = ex;
    if (t == 255) bbase[256] = s[255];
}

// ---- partition edges into buckets, packed (src<<9 | dst&511) ----
__global__ void __launch_bounds__(256)
k_part(const int* __restrict__ src, const int* __restrict__ dst,
       int* __restrict__ bcur, unsigned* __restrict__ pass1, int E) {
    __shared__ unsigned pk[4096];
    __shared__ unsigned char bk[4096];
    __shared__ int h[256];
    __shared__ int cur[256];
    int tid = threadIdx.x;
    h[tid] = 0;
    __syncthreads();
    int base = blockIdx.x * 4096;
#pragma unroll
    for (int i = 0; i < 16; ++i) {
        int li = i * 256 + tid;
        int e = base + li;
        if (e < E) {
            int s = src[e], d = dst[e];
            int b = d >> 9;
            pk[li] = ((unsigned)s << 9) | ((unsigned)d & 511u);
            bk[li] = (unsigned char)b;
            atomicAdd(&h[b], 1);
        } else {
            bk[li] = 255;
            pk[li] = 0xFFFFFFFFu;
        }
    }
    __syncthreads();
    {
        int c = h[tid];
        int run = c ? atomicAdd(&bcur[tid], c) : 0;
        cur[tid] = run;
    }
    __syncthreads();
#pragma unroll
    for (int i = 0; i < 16; ++i) {
        int li = i * 256 + tid;
        int e = base + li;
        if (e < E) {
            int b = bk[li];
            int pos = atomicAdd(&cur[b], 1);
            pass1[pos] = pk[li];
        }
    }
}

// ---- per-bucket CSR finish: node hist -> LDS scan -> offs/dinv -> scatter ----
__global__ void __launch_bounds__(512)
k_csr(const unsigned* __restrict__ pass1, const int* __restrict__ bbase,
      int* __restrict__ offs, float* __restrict__ dinv, int* __restrict__ esrc,
      int n, int E) {
    __shared__ int hist[512];
    __shared__ int cur[512];
    int tid = threadIdx.x;
    int b = blockIdx.x;
    hist[tid] = 0;
    __syncthreads();
    int beg = bbase[b], end = bbase[b + 1];
    for (int j = beg + tid; j < end; j += 512)
        atomicAdd(&hist[pass1[j] & 511u], 1);
    __syncthreads();
    int v = hist[tid];
    for (int off = 1; off < 512; off <<= 1) {        // inclusive scan
        int x = (tid >= off) ? hist[tid - off] : 0;
        __syncthreads();
        hist[tid] += x;
        __syncthreads();
    }
    int excl = hist[tid] - v;
    int node = (b << 9) + tid;
    if (node < n) {
        offs[node] = beg + excl;
        dinv[node] = rsqrtf((float)v + 1.0f);
    }
    cur[tid] = excl;
    if (b == 0 && tid == 0) offs[n] = E;
    __syncthreads();
    for (int j = beg + tid; j < end; j += 512) {
        unsigned u = pass1[j];
        int loc = (int)(u & 511u);
        int r = atomicAdd(&cur[loc], 1);
        esrc[beg + r] = (int)(u >> 9);
    }
}

// ---- MFMA GEMM: H[n,64] = (X[n,64] @ W[64,64]) * (SCALE? dinv[row] : 1) (+bias if OUT_F32) ----
template <bool IN_BF16, bool OUT_F32, bool SCALE>
__global__ void __launch_bounds__(256)
k_gemm_mfma(const void* __restrict__ Xv, const unsigned short* __restrict__ Wpk,
            const float* __restrict__ bias, const float* __restrict__ rowscale,
            void* __restrict__ Hv, int n) {
    int lane = threadIdx.x & 63;
    int wid = (blockIdx.x << 2) + (threadIdx.x >> 6);
    int nw = gridDim.x << 2;
    int T = (n + 15) >> 4;
    BF8 bfr[8];
    const uint4* wp = (const uint4*)Wpk;
#pragma unroll
    for (int f = 0; f < 8; ++f) bfr[f].q = wp[f * 64 + lane];
    int mrow = lane & 15, kq = lane >> 4, colb = lane & 15;
    float bb0 = 0.f, bb1 = 0.f, bb2 = 0.f, bb3 = 0.f;
    if (OUT_F32) {
        bb0 = bias[colb]; bb1 = bias[16 + colb];
        bb2 = bias[32 + colb]; bb3 = bias[48 + colb];
    }
    for (int t = wid; t < T; t += nw) {
        int rb = t << 4;
        int row = rb + mrow;
        bool ok = row < n;
        BF8 a0, a1;
        if (IN_BF16) {
            const uint4* xr = (const uint4*)((const unsigned short*)Xv + ((unsigned)row << 6));
            a0.q = ok ? xr[kq]     : make_uint4(0, 0, 0, 0);
            a1.q = ok ? xr[kq + 4] : make_uint4(0, 0, 0, 0);
        } else {
            const float4* xr = (const float4*)((const float*)Xv + ((unsigned)row << 6));
            float4 z = make_float4(0.f, 0.f, 0.f, 0.f);
            float4 p0 = ok ? xr[kq * 2]     : z;
            float4 p1 = ok ? xr[kq * 2 + 1] : z;
            float4 p2 = ok ? xr[8 + kq * 2] : z;
            float4 p3 = ok ? xr[8 + kq * 2 + 1] : z;
            a0.u[0] = f2bf(p0.x); a0.u[1] = f2bf(p0.y); a0.u[2] = f2bf(p0.z); a0.u[3] = f2bf(p0.w);
            a0.u[4] = f2bf(p1.x); a0.u[5] = f2bf(p1.y); a0.u[6] = f2bf(p1.z); a0.u[7] = f2bf(p1.w);
            a1.u[0] = f2bf(p2.x); a1.u[1] = f2bf(p2.y); a1.u[2] = f2bf(p2.z); a1.u[3] = f2bf(p2.w);
            a1.u[4] = f2bf(p3.x); a1.u[5] = f2bf(p3.y); a1.u[6] = f2bf(p3.z); a1.u[7] = f2bf(p3.w);
        }
        f32x4 acc0 = {0.f, 0.f, 0.f, 0.f}, acc1 = acc0, acc2 = acc0, acc3 = acc0;
        acc0 = __builtin_amdgcn_mfma_f32_16x16x32_bf16(a0.v, bfr[0].v, acc0, 0, 0, 0);
        acc0 = __builtin_amdgcn_mfma_f32_16x16x32_bf16(a1.v, bfr[1].v, acc0, 0, 0, 0);
        acc1 = __builtin_amdgcn_mfma_f32_16x16x32_bf16(a0.v, bfr[2].v, acc1, 0, 0, 0);
        acc1 = __builtin_amdgcn_mfma_f32_16x16x32_bf16(a1.v, bfr[3].v, acc1, 0, 0, 0);
        acc2 = __builtin_amdgcn_mfma_f32_16x16x32_bf16(a0.v, bfr[4].v, acc2, 0, 0, 0);
        acc2 = __builtin_amdgcn_mfma_f32_16x16x32_bf16(a1.v, bfr[5].v, acc2, 0, 0, 0);
        acc3 = __builtin_amdgcn_mfma_f32_16x16x32_bf16(a0.v, bfr[6].v, acc3, 0, 0, 0);
        acc3 = __builtin_amdgcn_mfma_f32_16x16x32_bf16(a1.v, bfr[7].v, acc3, 0, 0, 0);
        int rowb = rb + (kq << 2);
        if (OUT_F32) {
            float* O = (float*)Hv;
#pragma unroll
            for (int i = 0; i < 4; ++i) {
                if (rowb + i >= n) break;
                unsigned ro = (unsigned)(rowb + i) << 6;
                O[ro + colb]      = acc0[i] + bb0;
                O[ro + 16 + colb] = acc1[i] + bb1;
                O[ro + 32 + colb] = acc2[i] + bb2;
                O[ro + 48 + colb] = acc3[i] + bb3;
            }
        } else {
            unsigned short* O = (unsigned short*)Hv;
#pragma unroll
            for (int i = 0; i < 4; ++i) {
                if (rowb + i >= n) break;
                float sc = SCALE ? rowscale[rowb + i] : 1.0f;
                unsigned ro = (unsigned)(rowb + i) << 6;
                O[ro + colb]      = f2bf(acc0[i] * sc);
                O[ro + 16 + colb] = f2bf(acc1[i] * sc);
                O[ro + 32 + colb] = f2bf(acc2[i] * sc);
                O[ro + 48 + colb] = f2bf(acc3[i] * sc);
            }
        }
    }
}

// ---- aggregation: one wave/node, 8 edge-slots x 8 lanes x 16B gathers.
// Hs is pre-scaled by dinv[src]; out = dinv[node]*(sum + Hs[node]) + bias.
__global__ void __launch_bounds__(256)
k_agg(const int* __restrict__ offs, const int* __restrict__ esrc,
      const float* __restrict__ dinv, const unsigned short* __restrict__ Hs,
      const float* __restrict__ bias, unsigned short* __restrict__ out,
      int n, int relu) {
    int node = blockIdx.x * 4 + (threadIdx.x >> 6);
    if (node >= n) return;
    int lane = threadIdx.x & 63;
    int g = lane >> 3, h8 = lane & 7;
    int beg = offs[node], end = offs[node + 1];
    float a0 = 0.f, a1 = 0.f, a2 = 0.f, a3 = 0.f, a4 = 0.f, a5 = 0.f, a6 = 0.f, a7 = 0.f;
    int j = beg + g;
    if (j < end) {
        int s = esrc[j];
        for (;;) {
            int jn = j + 8;
            bool more = jn < end;
            int sn = more ? esrc[jn] : 0;               // prefetch next index
            uint4 hv = *(const uint4*)(Hs + ((unsigned)s << 6) + (h8 << 3));
            a0 += bflo(hv.x); a1 += bfhi(hv.x);
            a2 += bflo(hv.y); a3 += bfhi(hv.y);
            a4 += bflo(hv.z); a5 += bfhi(hv.z);
            a6 += bflo(hv.w); a7 += bfhi(hv.w);
            if (!more) break;
            s = sn; j = jn;
        }
    }
#pragma unroll
    for (int m = 8; m < 64; m <<= 1) {
        a0 += __shfl_xor(a0, m); a1 += __shfl_xor(a1, m);
        a2 += __shfl_xor(a2, m); a3 += __shfl_xor(a3, m);
        a4 += __shfl_xor(a4, m); a5 += __shfl_xor(a5, m);
        a6 += __shfl_xor(a6, m); a7 += __shfl_xor(a7, m);
    }
    if (g == 0) {
        float dd = dinv[node];
        uint4 sv = *(const uint4*)(Hs + ((unsigned)node << 6) + (h8 << 3));
        const float4* b4 = (const float4*)bias;
        float4 bA = b4[h8 * 2], bB = b4[h8 * 2 + 1];
        float r0 = (a0 + bflo(sv.x)) * dd + bA.x;
        float r1 = (a1 + bfhi(sv.x)) * dd + bA.y;
        float r2 = (a2 + bflo(sv.y)) * dd + bA.z;
        float r3 = (a3 + bfhi(sv.y)) * dd + bA.w;
        float r4 = (a4 + bflo(sv.z)) * dd + bB.x;
        float r5 = (a5 + bfhi(sv.z)) * dd + bB.y;
        float r6 = (a6 + bflo(sv.w)) * dd + bB.z;
        float r7 = (a7 + bfhi(sv.w)) * dd + bB.w;
        if (relu) {
            r0 = fmaxf(r0, 0.f); r1 = fmaxf(r1, 0.f); r2 = fmaxf(r2, 0.f); r3 = fmaxf(r3, 0.f);
            r4 = fmaxf(r4, 0.f); r5 = fmaxf(r5, 0.f); r6 = fmaxf(r6, 0.f); r7 = fmaxf(r7, 0.f);
        }
        uint4 o;
        o.x = packbf(r0, r1); o.y = packbf(r2, r3);
        o.z = packbf(r4, r5); o.w = packbf(r6, r7);
        *(uint4*)(out + ((unsigned)node << 6) + (h8 << 3)) = o;
    }
}

extern "C" void kernel_launch(void* const* d_in, const int* in_sizes, int n_in,
                              void* d_out, int out_size, void* d_ws, size_t ws_size,
                              hipStream_t stream) {
    const float* x  = (const float*)d_in[0];
    const int*   ei = (const int*)d_in[1];   // [2][E] int32
    const float* W1 = (const float*)d_in[2];
    const float* b1 = (const float*)d_in[3];
    const float* W2 = (const float*)d_in[4];
    const float* b2 = (const float*)d_in[5];
    const float* Wl = (const float*)d_in[6];
    const float* bl = (const float*)d_in[7];
    float* out = (float*)d_out;

    const int n = in_sizes[0] / FEAT;   // 100000
    const int E = in_sizes[1] / 2;      // 1200000
    const int* src = ei;
    const int* dst = ei + E;

    const int B = 256;
    const int NB = (n + 511) >> 9;            // 196 buckets
    const int pblocks = (E + 4095) / 4096;
    const int agg_blocks  = (n + 3) / 4;
    const int T = (n + 15) / 16;
    const int gemm_blocks = (T + 3) / 4;

    char* w = (char*)d_ws;
    int*   bcnt     = (int*)w;              w += 256 * 4;
    int*   bbase    = (int*)w;              w += 260 * 4;
    int*   bcur     = (int*)w;              w += 256 * 4;
    int*   offs     = (int*)w;              w += ((size_t)n + 4) * 4;
    float* dinv     = (float*)w;            w += (size_t)n * 4;
    w = (char*)(((uintptr_t)w + 15) & ~(uintptr_t)15);
    unsigned short* Wpk = (unsigned short*)w;  w += 3 * 4096 * 2;
    unsigned* pass1 = (unsigned*)w;         w += (size_t)E * 4;
    int*   esrc     = (int*)w;              w += (size_t)E * 4;
    unsigned short* bufA = (unsigned short*)w;  w += (size_t)n * FEAT * 2;  // Hs1 / Hs3
    unsigned short* bufB = (unsigned short*)w;                              // h2 / t

    // ---- prep: W pack + bcnt zero ----
    k_prepw<<<dim3(4), dim3(B), 0, stream>>>(W1, W2, Wl, Wpk, bcnt);

    // ---- CSR build ----
    k_bhist<<<dim3(256), dim3(B), 0, stream>>>(dst, bcnt, E);
    k_bscan<<<dim3(1), dim3(B), 0, stream>>>(bcnt, bbase, bcur);
    k_part<<<dim3(pblocks), dim3(B), 0, stream>>>(src, dst, bcur, pass1, E);
    k_csr<<<dim3(NB), dim3(512), 0, stream>>>(pass1, bbase, offs, dinv, esrc, n, E);

    // ---- layer 1: Hs1 = (x@W1)*dinv ----
    k_gemm_mfma<false, false, true><<<dim3(gemm_blocks), dim3(B), 0, stream>>>(x, Wpk, nullptr, dinv, bufA, n);
    k_agg<<<dim3(agg_blocks), dim3(B), 0, stream>>>(offs, esrc, dinv, bufA, b1, bufB, n, 1);

    // ---- layer 2: Hs3 = (h2@W2)*dinv ----
    k_gemm_mfma<true, false, true><<<dim3(gemm_blocks), dim3(B), 0, stream>>>(bufB, Wpk + 4096, nullptr, dinv, bufA, n);
    k_agg<<<dim3(agg_blocks), dim3(B), 0, stream>>>(offs, esrc, dinv, bufA, b2, bufB, n, 0);

    // ---- final linear: out = t@Wl + bl (fp32) ----
    k_gemm_mfma<true, true, false><<<dim3(gemm_blocks), dim3(B), 0, stream>>>(bufB, Wpk + 8192, bl, nullptr, out, n);
}

// Round 10
// 247.534 us; speedup vs baseline: 2.1302x; 1.0482x over previous
//
#include <hip/hip_runtime.h>
#include <hip/hip_bf16.h>

// 2-layer GCN, N=100000, E=1200000, dims 64, fp32 in/out.
//
// R10: (1) agg: 8 nodes/wave x 8 lanes/node, serial edges w/ depth-2
// pipeline + weight-0 fmaf masking -> NO shuffle reduce (was ~half the
// VALU). (2) gemm: column-permuted W pack (tile c -> col n*4+c) so the 4
// accumulators per lane are adjacent columns -> 8B/16B vector stores (was
// 16 scalar stores), float4 bias; v_cvt_pk_bf16_f32 packed converts.
// 2 tiles/wave. CSR build (R8/R9) unchanged.

#define FEAT 64

typedef __attribute__((ext_vector_type(8))) short bf16x8;
typedef __attribute__((ext_vector_type(4))) float f32x4;
union BF8 { bf16x8 v; unsigned short u[8]; unsigned pk[4]; uint4 q; };

__device__ __forceinline__ unsigned short f2bf(float f) {
    unsigned u = __float_as_uint(f);
    return (unsigned short)((u + 0x7FFFu + ((u >> 16) & 1u)) >> 16);   // RNE
}
__device__ __forceinline__ float bflo(unsigned u) { return __uint_as_float(u << 16); }
__device__ __forceinline__ float bfhi(unsigned u) { return __uint_as_float(u & 0xFFFF0000u); }
__device__ __forceinline__ unsigned pk2bf(float a, float b) {   // v_cvt_pk_bf16_f32
    union { __hip_bfloat162 b; unsigned u; } cv;
    cv.b = __float22bfloat162_rn(make_float2(a, b));
    return cv.u;
}

// ---- W pre-pack into MFMA B-fragment layout (blocks 0-2) + zero bcnt (block 3).
// Column permutation: fragment pair c covers output cols n*4+c (n = lane&15).
__global__ void k_prepw(const float* __restrict__ W1, const float* __restrict__ W2,
                        const float* __restrict__ Wl, unsigned short* __restrict__ P,
                        int* __restrict__ bcnt) {
    if (blockIdx.x == 3) {
        if (threadIdx.x < 256) bcnt[threadIdx.x] = 0;
        return;
    }
    const float* W = (blockIdx.x == 0) ? W1 : (blockIdx.x == 1) ? W2 : Wl;
    unsigned short* p = P + blockIdx.x * 4096;
    for (int i = threadIdx.x; i < 4096; i += 256) {
        int c = i >> 10, s = (i >> 9) & 1, l = (i >> 3) & 63, j = i & 7;
        int k = s * 32 + ((l >> 4) << 3) + j;
        int col = ((l & 15) << 2) + c;          // permuted: lane n -> cols 4n..4n+3
        p[i] = f2bf(W[k * 64 + col]);
    }
}

// ---- bucket histogram (bucket = dst >> 9) ----
__global__ void __launch_bounds__(256)
k_bhist(const int* __restrict__ dst, int* __restrict__ bcnt, int E) {
    __shared__ int h[256];
    int tid = threadIdx.x;
    h[tid] = 0;
    __syncthreads();
    int stride = gridDim.x * 256;
    for (int e = blockIdx.x * 256 + tid; e < E; e += stride)
        atomicAdd(&h[dst[e] >> 9], 1);
    __syncthreads();
    if (h[tid]) atomicAdd(&bcnt[tid], h[tid]);
}

// ---- exclusive scan of 256 bucket counts -> bbase (257 wide) + bcur ----
__global__ void k_bscan(const int* __restrict__ bcnt, int* __restrict__ bbase,
                        int* __restrict__ bcur) {
    __shared__ int s[256];
    int t = threadIdx.x;
    int v = bcnt[t];
    s[t] = v;
    __syncthreads();
    for (int off = 1; off < 256; off <<= 1) {
        int x = (t >= off) ? s[t - off] : 0;
        __syncthreads();
        s[t] += x;
        __syncthreads();
    }
    int ex = s[t] - v;
    bbase[t] = ex;
    bcur[t] = ex;
    if (t == 255) bbase[256] = s[255];
}

// ---- partition edges into buckets, packed (src<<9 | dst&511) ----
__global__ void __launch_bounds__(256)
k_part(const int* __restrict__ src, const int* __restrict__ dst,
       int* __restrict__ bcur, unsigned* __restrict__ pass1, int E) {
    __shared__ unsigned pk[4096];
    __shared__ unsigned char bk[4096];
    __shared__ int h[256];
    __shared__ int cur[256];
    int tid = threadIdx.x;
    h[tid] = 0;
    __syncthreads();
    int base = blockIdx.x * 4096;
#pragma unroll
    for (int i = 0; i < 16; ++i) {
        int li = i * 256 + tid;
        int e = base + li;
        if (e < E) {
            int s = src[e], d = dst[e];
            int b = d >> 9;
            pk[li] = ((unsigned)s << 9) | ((unsigned)d & 511u);
            bk[li] = (unsigned char)b;
            atomicAdd(&h[b], 1);
        } else {
            bk[li] = 255;
            pk[li] = 0xFFFFFFFFu;
        }
    }
    __syncthreads();
    {
        int c = h[tid];
        int run = c ? atomicAdd(&bcur[tid], c) : 0;
        cur[tid] = run;
    }
    __syncthreads();
#pragma unroll
    for (int i = 0; i < 16; ++i) {
        int li = i * 256 + tid;
        int e = base + li;
        if (e < E) {
            int b = bk[li];
            int pos = atomicAdd(&cur[b], 1);
            pass1[pos] = pk[li];
        }
    }
}

// ---- per-bucket CSR finish: node hist -> LDS scan -> offs/dinv -> scatter ----
__global__ void __launch_bounds__(512)
k_csr(const unsigned* __restrict__ pass1, const int* __restrict__ bbase,
      int* __restrict__ offs, float* __restrict__ dinv, int* __restrict__ esrc,
      int n, int E) {
    __shared__ int hist[512];
    __shared__ int cur[512];
    int tid = threadIdx.x;
    int b = blockIdx.x;
    hist[tid] = 0;
    __syncthreads();
    int beg = bbase[b], end = bbase[b + 1];
    for (int j = beg + tid; j < end; j += 512)
        atomicAdd(&hist[pass1[j] & 511u], 1);
    __syncthreads();
    int v = hist[tid];
    for (int off = 1; off < 512; off <<= 1) {        // inclusive scan
        int x = (tid >= off) ? hist[tid - off] : 0;
        __syncthreads();
        hist[tid] += x;
        __syncthreads();
    }
    int excl = hist[tid] - v;
    int node = (b << 9) + tid;
    if (node < n) {
        offs[node] = beg + excl;
        dinv[node] = rsqrtf((float)v + 1.0f);
    }
    cur[tid] = excl;
    if (b == 0 && tid == 0) offs[n] = E;
    __syncthreads();
    for (int j = beg + tid; j < end; j += 512) {
        unsigned u = pass1[j];
        int loc = (int)(u & 511u);
        int r = atomicAdd(&cur[loc], 1);
        esrc[beg + r] = (int)(u >> 9);
    }
}

// ---- MFMA GEMM: H[n,64] = (X @ W) * (SCALE? dinv[row] : 1) (+bias if OUT_F32).
// Column-permuted: lane (n=lane&15) holds output cols 4n..4n+3 -> vector stores.
template <bool IN_BF16, bool OUT_F32, bool SCALE>
__global__ void __launch_bounds__(256)
k_gemm_mfma(const void* __restrict__ Xv, const unsigned short* __restrict__ Wpk,
            const float* __restrict__ bias, const float* __restrict__ rowscale,
            void* __restrict__ Hv, int n) {
    int lane = threadIdx.x & 63;
    int wid = (blockIdx.x << 2) + (threadIdx.x >> 6);
    int nw = gridDim.x << 2;
    int T = (n + 15) >> 4;
    BF8 bfr[8];
    const uint4* wp = (const uint4*)Wpk;
#pragma unroll
    for (int f = 0; f < 8; ++f) bfr[f].q = wp[f * 64 + lane];
    int mrow = lane & 15, kq = lane >> 4, colb = lane & 15;
    float4 bv4 = make_float4(0.f, 0.f, 0.f, 0.f);
    if (OUT_F32) bv4 = ((const float4*)bias)[colb];     // cols 4c..4c+3
    for (int t = wid; t < T; t += nw) {
        int rb = t << 4;
        int row = rb + mrow;
        bool ok = row < n;
        BF8 a0, a1;
        if (IN_BF16) {
            const uint4* xr = (const uint4*)((const unsigned short*)Xv + ((unsigned)row << 6));
            a0.q = ok ? xr[kq]     : make_uint4(0, 0, 0, 0);
            a1.q = ok ? xr[kq + 4] : make_uint4(0, 0, 0, 0);
        } else {
            const float4* xr = (const float4*)((const float*)Xv + ((unsigned)row << 6));
            float4 z = make_float4(0.f, 0.f, 0.f, 0.f);
            float4 p0 = ok ? xr[kq * 2]     : z;
            float4 p1 = ok ? xr[kq * 2 + 1] : z;
            float4 p2 = ok ? xr[8 + kq * 2] : z;
            float4 p3 = ok ? xr[8 + kq * 2 + 1] : z;
            a0.pk[0] = pk2bf(p0.x, p0.y); a0.pk[1] = pk2bf(p0.z, p0.w);
            a0.pk[2] = pk2bf(p1.x, p1.y); a0.pk[3] = pk2bf(p1.z, p1.w);
            a1.pk[0] = pk2bf(p2.x, p2.y); a1.pk[1] = pk2bf(p2.z, p2.w);
            a1.pk[2] = pk2bf(p3.x, p3.y); a1.pk[3] = pk2bf(p3.z, p3.w);
        }
        f32x4 acc0 = {0.f, 0.f, 0.f, 0.f}, acc1 = acc0, acc2 = acc0, acc3 = acc0;
        acc0 = __builtin_amdgcn_mfma_f32_16x16x32_bf16(a0.v, bfr[0].v, acc0, 0, 0, 0);
        acc0 = __builtin_amdgcn_mfma_f32_16x16x32_bf16(a1.v, bfr[1].v, acc0, 0, 0, 0);
        acc1 = __builtin_amdgcn_mfma_f32_16x16x32_bf16(a0.v, bfr[2].v, acc1, 0, 0, 0);
        acc1 = __builtin_amdgcn_mfma_f32_16x16x32_bf16(a1.v, bfr[3].v, acc1, 0, 0, 0);
        acc2 = __builtin_amdgcn_mfma_f32_16x16x32_bf16(a0.v, bfr[4].v, acc2, 0, 0, 0);
        acc2 = __builtin_amdgcn_mfma_f32_16x16x32_bf16(a1.v, bfr[5].v, acc2, 0, 0, 0);
        acc3 = __builtin_amdgcn_mfma_f32_16x16x32_bf16(a0.v, bfr[6].v, acc3, 0, 0, 0);
        acc3 = __builtin_amdgcn_mfma_f32_16x16x32_bf16(a1.v, bfr[7].v, acc3, 0, 0, 0);
        int rowb = rb + (kq << 2);
        if (OUT_F32) {
            float* O = (float*)Hv;
#pragma unroll
            for (int i = 0; i < 4; ++i) {
                if (rowb + i >= n) break;
                unsigned ro = (unsigned)(rowb + i) << 6;
                float4 o = make_float4(acc0[i] + bv4.x, acc1[i] + bv4.y,
                                       acc2[i] + bv4.z, acc3[i] + bv4.w);
                *(float4*)(O + ro + (colb << 2)) = o;
            }
        } else {
            unsigned short* O = (unsigned short*)Hv;
#pragma unroll
            for (int i = 0; i < 4; ++i) {
                if (rowb + i >= n) break;
                float sc = SCALE ? rowscale[rowb + i] : 1.0f;
                unsigned ro = (unsigned)(rowb + i) << 6;
                uint2 o = make_uint2(pk2bf(acc0[i] * sc, acc1[i] * sc),
                                     pk2bf(acc2[i] * sc, acc3[i] * sc));
                *(uint2*)(O + ro + (colb << 2)) = o;
            }
        }
    }
}

// ---- aggregation: 8 nodes per wave x 8 lanes per node, serial edges,
// depth-2 pipelined gathers, weight-0 fmaf masking, NO shuffle reduce.
// Hs pre-scaled by dinv[src]; out = dinv[node]*(sum + Hs[node]) + bias.
template <bool RELU>
__global__ void __launch_bounds__(256)
k_agg(const int* __restrict__ offs, const int* __restrict__ esrc,
      const float* __restrict__ dinv, const unsigned short* __restrict__ Hs,
      const float* __restrict__ bias, unsigned short* __restrict__ out, int n) {
    int lane = threadIdx.x & 63;
    int h8 = lane & 7;
    int node = blockIdx.x * 32 + ((threadIdx.x >> 6) << 3) + (lane >> 3);
    bool nok = node < n;
    int beg = 0, end = 0;
    if (nok) { beg = offs[node]; end = offs[node + 1]; }
    float a0 = 0.f, a1 = 0.f, a2 = 0.f, a3 = 0.f, a4 = 0.f, a5 = 0.f, a6 = 0.f, a7 = 0.f;
    int j = beg;
    int s0 = 0, s1 = 0;
    float w0 = 0.f, w1 = 0.f;
    if (j < end)     { s0 = esrc[j];     w0 = 1.f; }
    if (j + 1 < end) { s1 = esrc[j + 1]; w1 = 1.f; }
    while (__ballot(j < end)) {
        uint4 h0 = *(const uint4*)(Hs + ((unsigned)s0 << 6) + (h8 << 3));
        uint4 h1 = *(const uint4*)(Hs + ((unsigned)s1 << 6) + (h8 << 3));
        int jn = j + 2;
        int t0 = s0, t1 = s1;
        float v0 = 0.f, v1 = 0.f;
        if (jn < end)     { t0 = esrc[jn];     v0 = 1.f; }
        if (jn + 1 < end) { t1 = esrc[jn + 1]; v1 = 1.f; }
        a0 = fmaf(bflo(h0.x), w0, a0); a1 = fmaf(bfhi(h0.x), w0, a1);
        a2 = fmaf(bflo(h0.y), w0, a2); a3 = fmaf(bfhi(h0.y), w0, a3);
        a4 = fmaf(bflo(h0.z), w0, a4); a5 = fmaf(bfhi(h0.z), w0, a5);
        a6 = fmaf(bflo(h0.w), w0, a6); a7 = fmaf(bfhi(h0.w), w0, a7);
        a0 = fmaf(bflo(h1.x), w1, a0); a1 = fmaf(bfhi(h1.x), w1, a1);
        a2 = fmaf(bflo(h1.y), w1, a2); a3 = fmaf(bfhi(h1.y), w1, a3);
        a4 = fmaf(bflo(h1.z), w1, a4); a5 = fmaf(bfhi(h1.z), w1, a5);
        a6 = fmaf(bflo(h1.w), w1, a6); a7 = fmaf(bfhi(h1.w), w1, a7);
        j = jn; s0 = t0; s1 = t1; w0 = v0; w1 = v1;
    }
    if (nok) {
        float dd = dinv[node];
        uint4 sv = *(const uint4*)(Hs + ((unsigned)node << 6) + (h8 << 3));
        const float4* b4 = (const float4*)bias;
        float4 bA = b4[h8 * 2], bB = b4[h8 * 2 + 1];
        float r0 = (a0 + bflo(sv.x)) * dd + bA.x;
        float r1 = (a1 + bfhi(sv.x)) * dd + bA.y;
        float r2 = (a2 + bflo(sv.y)) * dd + bA.z;
        float r3 = (a3 + bfhi(sv.y)) * dd + bA.w;
        float r4 = (a4 + bflo(sv.z)) * dd + bB.x;
        float r5 = (a5 + bfhi(sv.z)) * dd + bB.y;
        float r6 = (a6 + bflo(sv.w)) * dd + bB.z;
        float r7 = (a7 + bfhi(sv.w)) * dd + bB.w;
        if (RELU) {
            r0 = fmaxf(r0, 0.f); r1 = fmaxf(r1, 0.f); r2 = fmaxf(r2, 0.f); r3 = fmaxf(r3, 0.f);
            r4 = fmaxf(r4, 0.f); r5 = fmaxf(r5, 0.f); r6 = fmaxf(r6, 0.f); r7 = fmaxf(r7, 0.f);
        }
        uint4 o = make_uint4(pk2bf(r0, r1), pk2bf(r2, r3), pk2bf(r4, r5), pk2bf(r6, r7));
        *(uint4*)(out + ((unsigned)node << 6) + (h8 << 3)) = o;
    }
}

extern "C" void kernel_launch(void* const* d_in, const int* in_sizes, int n_in,
                              void* d_out, int out_size, void* d_ws, size_t ws_size,
                              hipStream_t stream) {
    const float* x  = (const float*)d_in[0];
    const int*   ei = (const int*)d_in[1];   // [2][E] int32
    const float* W1 = (const float*)d_in[2];
    const float* b1 = (const float*)d_in[3];
    const float* W2 = (const float*)d_in[4];
    const float* b2 = (const float*)d_in[5];
    const float* Wl = (const float*)d_in[6];
    const float* bl = (const float*)d_in[7];
    float* out = (float*)d_out;

    const int n = in_sizes[0] / FEAT;   // 100000
    const int E = in_sizes[1] / 2;      // 1200000
    const int* src = ei;
    const int* dst = ei + E;

    const int B = 256;
    const int NB = (n + 511) >> 9;            // 196 buckets
    const int pblocks = (E + 4095) / 4096;
    const int agg_blocks  = (n + 31) / 32;
    const int T = (n + 15) / 16;
    const int gemm_blocks = (T + 7) / 8;      // ~2 tiles per wave

    char* w = (char*)d_ws;
    int*   bcnt     = (int*)w;              w += 256 * 4;
    int*   bbase    = (int*)w;              w += 260 * 4;
    int*   bcur     = (int*)w;              w += 256 * 4;
    int*   offs     = (int*)w;              w += ((size_t)n + 4) * 4;
    float* dinv     = (float*)w;            w += (size_t)n * 4;
    w = (char*)(((uintptr_t)w + 15) & ~(uintptr_t)15);
    unsigned short* Wpk = (unsigned short*)w;  w += 3 * 4096 * 2;
    unsigned* pass1 = (unsigned*)w;         w += (size_t)E * 4;
    int*   esrc     = (int*)w;              w += (size_t)E * 4;
    unsigned short* bufA = (unsigned short*)w;  w += (size_t)n * FEAT * 2;  // Hs1 / Hs3
    unsigned short* bufB = (unsigned short*)w;                              // h2 / t

    // ---- prep: W pack + bcnt zero ----
    k_prepw<<<dim3(4), dim3(B), 0, stream>>>(W1, W2, Wl, Wpk, bcnt);

    // ---- CSR build ----
    k_bhist<<<dim3(256), dim3(B), 0, stream>>>(dst, bcnt, E);
    k_bscan<<<dim3(1), dim3(B), 0, stream>>>(bcnt, bbase, bcur);
    k_part<<<dim3(pblocks), dim3(B), 0, stream>>>(src, dst, bcur, pass1, E);
    k_csr<<<dim3(NB), dim3(512), 0, stream>>>(pass1, bbase, offs, dinv, esrc, n, E);

    // ---- layer 1: Hs1 = (x@W1)*dinv ----
    k_gemm_mfma<false, false, true><<<dim3(gemm_blocks), dim3(B), 0, stream>>>(x, Wpk, nullptr, dinv, bufA, n);
    k_agg<true><<<dim3(agg_blocks), dim3(B), 0, stream>>>(offs, esrc, dinv, bufA, b1, bufB, n);

    // ---- layer 2: Hs3 = (h2@W2)*dinv ----
    k_gemm_mfma<true, false, true><<<dim3(gemm_blocks), dim3(B), 0, stream>>>(bufB, Wpk + 4096, nullptr, dinv, bufA, n);
    k_agg<false><<<dim3(agg_blocks), dim3(B), 0, stream>>>(offs, esrc, dinv, bufA, b2, bufB, n);

    // ---- final linear: out = t@Wl + bl (fp32) ----
    k_gemm_mfma<true, true, false><<<dim3(gemm_blocks), dim3(B), 0, stream>>>(bufB, Wpk + 8192, bl, nullptr, out, n);
}